// Round 2
// baseline (1132.408 us; speedup 1.0000x reference)
//
#include <hip/hip_runtime.h>
#include <math.h>

#define N_NODES 50000
#define N_EDGES 1000000
#define HID 64

__device__ __forceinline__ float waveReduceSum64(float v) {
    #pragma unroll
    for (int o = 32; o > 0; o >>= 1) v += __shfl_xor(v, o, 64);
    return v;
}

// ---------------- node encoder: h = x @ W_node + b_node ----------------
__global__ __launch_bounds__(256) void k_node_encode(
    const float* __restrict__ x, const float* __restrict__ Wn,
    const float* __restrict__ bn, float* __restrict__ h) {
    int n = blockIdx.x * 4 + (threadIdx.x >> 6);
    int c = threadIdx.x & 63;
    if (n >= N_NODES) return;
    float acc = bn[c];
    const float* xr = x + n * 16;
    #pragma unroll
    for (int k = 0; k < 16; ++k) acc = fmaf(xr[k], Wn[k * 64 + c], acc);
    h[n * 64 + c] = acc;
}

// ---------------- edge CSR build ----------------
__global__ __launch_bounds__(256) void k_hist(const int* __restrict__ ei, int* __restrict__ cnt) {
    int i = blockIdx.x * blockDim.x + threadIdx.x;
    int stride = gridDim.x * blockDim.x;
    for (; i < N_EDGES; i += stride) atomicAdd(&cnt[ei[N_EDGES + i]], 1);
}

__global__ __launch_bounds__(256) void k_scan(const int* __restrict__ cnt,
                                              int* __restrict__ offs, int* __restrict__ cursor) {
    __shared__ int part[256];
    const int T = 256, M = N_NODES + 1;
    int t = threadIdx.x;
    int chunk = (M + T - 1) / T;
    int lo = t * chunk, hi = min(lo + chunk, M);
    int s = 0;
    for (int i = lo; i < hi; ++i) s += cnt[i];
    part[t] = s;
    __syncthreads();
    // single-block inclusive scan over 256 partials
    for (int d = 1; d < T; d <<= 1) {
        int v = (t >= d) ? part[t - d] : 0;
        __syncthreads();
        part[t] += v;
        __syncthreads();
    }
    int run = (t == 0) ? 0 : part[t - 1];
    for (int i = lo; i < hi; ++i) {
        offs[i] = run;
        if (i < N_NODES) cursor[i] = run;
        run += cnt[i];
    }
}

__global__ __launch_bounds__(256) void k_scatter(
    const int* __restrict__ ei, const float* __restrict__ eattr,
    int* __restrict__ cursor, int* __restrict__ s_src, float* __restrict__ s_ea) {
    int i = blockIdx.x * blockDim.x + threadIdx.x;
    int stride = gridDim.x * blockDim.x;
    for (; i < N_EDGES; i += stride) {
        int d = ei[N_EDGES + i];
        int p = atomicAdd(&cursor[d], 1);
        s_src[p] = ei[i];
        s_ea[p] = eattr[i];
    }
}

// ---------------- z = relu(LN(h, g, b)) (64 channels, one wave/node) ----------------
__global__ __launch_bounds__(256) void k_ln_relu(
    const float* __restrict__ h, const float* __restrict__ g,
    const float* __restrict__ b, float* __restrict__ z) {
    int wid = (blockIdx.x * blockDim.x + threadIdx.x) >> 6;
    int lane = threadIdx.x & 63;
    if (wid >= N_NODES) return;
    float v = h[wid * 64 + lane];
    float mu = waveReduceSum64(v) * (1.f / 64.f);
    float d = v - mu;
    float var = waveReduceSum64(d * d) * (1.f / 64.f);
    float zz = d * rsqrtf(var + 1e-5f) * g[lane] + b[lane];
    z[wid * 64 + lane] = fmaxf(zz, 0.f);
}

// ---------------- softmax aggregation, online, one wave per dst node ----------------
__global__ __launch_bounds__(256) void k_agg(
    const float* __restrict__ z, const int* __restrict__ offs,
    const int* __restrict__ s_src, const float* __restrict__ s_ea,
    const float* __restrict__ We, const float* __restrict__ be,
    const float* __restrict__ t, int layer, float* __restrict__ agg) {
    int wid = (blockIdx.x * blockDim.x + threadIdx.x) >> 6;
    int lane = threadIdx.x & 63;
    if (wid >= N_NODES) return;
    int beg = offs[wid], end = offs[wid + 1];
    float we = We[lane], bev = be[lane];
    float tl = t[layer];
    float m = -INFINITY, s = 0.f, num = 0.f;
    for (int i = beg; i < end; ++i) {
        int sj = s_src[i];
        float ea = s_ea[i];
        float msg = fmaxf(z[sj * 64 + lane] + fmaf(ea, we, bev), 0.f) + 1e-7f;
        float lg = msg * tl;
        float mn = fmaxf(m, lg);
        float corr = __expf(m - mn);   // m=-inf first iter -> 0, s=0 anyway
        float p = __expf(lg - mn);
        s = fmaf(s, corr, p);
        num = fmaf(num, corr, p * msg);
        m = mn;
    }
    agg[wid * 64 + lane] = num / (s + 1e-16f);
}

// ---------------- fused MLP: h' = (agg+z)@W1+b1 -> LN -> relu -> @W2+b2 (+res) ----------------
__global__ __launch_bounds__(256) void k_mlp(
    const float* __restrict__ agg, const float* __restrict__ z,
    float* __restrict__ h, const float* __restrict__ W1, const float* __restrict__ b1,
    const float* __restrict__ g1, const float* __restrict__ be1,
    const float* __restrict__ W2, const float* __restrict__ b2, int addres) {
    __shared__ float w1[64 * 128];
    __shared__ float w2[128 * 64];
    for (int i = threadIdx.x; i < 8192; i += 256) {
        w1[i] = W1[i];
        w2[i] = W2[i];
    }
    __syncthreads();
    int lane = threadIdx.x & 63;
    int wave = threadIdx.x >> 6;
    int wid = blockIdx.x * 4 + wave;      // node group of 8
    const int NG = N_NODES / 8;           // 6250
    if (wid >= NG) return;
    float b1a = b1[lane], b1b = b1[64 + lane];
    float g1a = g1[lane], g1b = g1[64 + lane];
    float e1a = be1[lane], e1b = be1[64 + lane];
    float b2v = b2[lane];
    int n0 = wid * 8;
    float v[8], u0[8], u1[8], o[8];
    #pragma unroll
    for (int k = 0; k < 8; ++k) {
        int n = n0 + k;
        v[k] = agg[n * 64 + lane] + z[n * 64 + lane];
        u0[k] = b1a;
        u1[k] = b1b;
    }
    for (int c = 0; c < 64; ++c) {
        float w0 = w1[c * 128 + lane];
        float wB = w1[c * 128 + 64 + lane];
        #pragma unroll
        for (int k = 0; k < 8; ++k) {
            float vc = __shfl(v[k], c, 64);
            u0[k] = fmaf(vc, w0, u0[k]);
            u1[k] = fmaf(vc, wB, u1[k]);
        }
    }
    #pragma unroll
    for (int k = 0; k < 8; ++k) {
        float mu = waveReduceSum64(u0[k] + u1[k]) * (1.f / 128.f);
        float d0 = u0[k] - mu, d1 = u1[k] - mu;
        float var = waveReduceSum64(d0 * d0 + d1 * d1) * (1.f / 128.f);
        float rs = rsqrtf(var + 1e-5f);
        u0[k] = fmaxf(fmaf(d0 * rs, g1a, e1a), 0.f);
        u1[k] = fmaxf(fmaf(d1 * rs, g1b, e1b), 0.f);
        o[k] = b2v;
    }
    for (int j = 0; j < 64; ++j) {
        float wA = w2[j * 64 + lane];
        float wB = w2[(j + 64) * 64 + lane];
        #pragma unroll
        for (int k = 0; k < 8; ++k) {
            float a0 = __shfl(u0[k], j, 64);
            float a1 = __shfl(u1[k], j, 64);
            o[k] = fmaf(a0, wA, fmaf(a1, wB, o[k]));
        }
    }
    #pragma unroll
    for (int k = 0; k < 8; ++k) {
        int n = n0 + k;
        float r = addres ? (h[n * 64 + lane] + o[k]) : o[k];
        h[n * 64 + lane] = r;
    }
}

// ---------------- final LN/relu + global avg & max pool partials ----------------
__global__ __launch_bounds__(256) void k_pool(
    const float* __restrict__ h, const float* __restrict__ g, const float* __restrict__ b,
    float* __restrict__ psum, unsigned int* __restrict__ pmax) {
    int wid0 = (blockIdx.x * blockDim.x + threadIdx.x) >> 6;
    int lane = threadIdx.x & 63;
    int nw = (gridDim.x * blockDim.x) >> 6;
    float ga = g[lane], ba = b[lane];
    float lsum = 0.f, lmax = 0.f;
    for (int n = wid0; n < N_NODES; n += nw) {
        float v = h[n * 64 + lane];
        float mu = waveReduceSum64(v) * (1.f / 64.f);
        float d = v - mu;
        float var = waveReduceSum64(d * d) * (1.f / 64.f);
        float zz = fmaxf(d * rsqrtf(var + 1e-5f) * ga + ba, 0.f);
        lsum += zz;
        lmax = fmaxf(lmax, zz);
    }
    atomicAdd(&psum[lane], lsum);
    atomicMax(&pmax[lane], __float_as_uint(lmax)); // post-relu >= 0: uint order == float order
}

// ---------------- head: pool bins -> emb[64] @ W_lin + b_lin ----------------
__global__ __launch_bounds__(64) void k_head(
    const float* __restrict__ psum, const unsigned int* __restrict__ pmax,
    const float* __restrict__ Wl, const float* __restrict__ bl, float* __restrict__ out) {
    __shared__ float emb[64];
    int t = threadIdx.x;
    if (t < 32) {
        emb[t] = (psum[2 * t] + psum[2 * t + 1]) * (0.5f / (float)N_NODES);
    } else {
        int i = t - 32;
        emb[t] = fmaxf(__uint_as_float(pmax[2 * i]), __uint_as_float(pmax[2 * i + 1]));
    }
    __syncthreads();
    float acc = bl[t];
    for (int k = 0; k < 64; ++k) acc = fmaf(emb[k], Wl[k * 64 + t], acc);
    out[t] = acc;
}

extern "C" void kernel_launch(void* const* d_in, const int* in_sizes, int n_in,
                              void* d_out, int out_size, void* d_ws, size_t ws_size,
                              hipStream_t stream) {
    const float* x     = (const float*)d_in[0];
    const float* eattr = (const float*)d_in[1];
    const int*   ei    = (const int*)d_in[2];
    const float* Wn    = (const float*)d_in[3];
    const float* bn    = (const float*)d_in[4];
    const float* We    = (const float*)d_in[5];
    const float* be    = (const float*)d_in[6];
    const float* t     = (const float*)d_in[7];
    const float* W1    = (const float*)d_in[8];
    const float* b1    = (const float*)d_in[9];
    const float* lg    = (const float*)d_in[10];
    const float* lb    = (const float*)d_in[11];
    const float* W2    = (const float*)d_in[12];
    const float* b2    = (const float*)d_in[13];
    const float* ng    = (const float*)d_in[14];
    const float* nb    = (const float*)d_in[15];
    const float* Wl    = (const float*)d_in[16];
    const float* bl    = (const float*)d_in[17];
    float* out = (float*)d_out;

    char* p = (char*)d_ws;
    float* h   = (float*)p; p += (size_t)N_NODES * 64 * 4;
    float* z   = (float*)p; p += (size_t)N_NODES * 64 * 4;
    float* agg = (float*)p; p += (size_t)N_NODES * 64 * 4;
    int* s_src = (int*)p;   p += (size_t)N_EDGES * 4;
    float* s_ea = (float*)p; p += (size_t)N_EDGES * 4;
    int* cnt    = (int*)p;  p += (size_t)(N_NODES + 4) * 4;
    int* offs   = (int*)p;  p += (size_t)(N_NODES + 4) * 4;
    int* cursor = (int*)p;  p += (size_t)(N_NODES + 4) * 4;
    float* psum = (float*)p; p += 64 * 4;
    unsigned int* pmax = (unsigned int*)p; p += 64 * 4;

    hipMemsetAsync(cnt, 0, (N_NODES + 1) * sizeof(int), stream);
    hipMemsetAsync(psum, 0, 64 * sizeof(float), stream);
    hipMemsetAsync(pmax, 0, 64 * sizeof(unsigned int), stream);

    k_node_encode<<<(N_NODES + 3) / 4, 256, 0, stream>>>(x, Wn, bn, h);
    k_hist<<<1024, 256, 0, stream>>>(ei, cnt);
    k_scan<<<1, 256, 0, stream>>>(cnt, offs, cursor);
    k_scatter<<<1024, 256, 0, stream>>>(ei, eattr, cursor, s_src, s_ea);

    for (int i = 0; i < 3; ++i) {
        const float* zp;
        if (i > 0) {
            k_ln_relu<<<(N_NODES + 3) / 4, 256, 0, stream>>>(h, ng + i * 64, nb + i * 64, z);
            zp = z;
        } else {
            zp = h;
        }
        k_agg<<<(N_NODES + 3) / 4, 256, 0, stream>>>(zp, offs, s_src, s_ea, We, be, t, i, agg);
        k_mlp<<<(N_NODES / 8 + 3) / 4, 256, 0, stream>>>(
            agg, zp, h, W1 + (size_t)i * 64 * 128, b1 + i * 128, lg + i * 128, lb + i * 128,
            W2 + (size_t)i * 128 * 64, b2 + i * 64, i > 0);
    }

    k_pool<<<256, 256, 0, stream>>>(h, ng, nb, psum, pmax);
    k_head<<<1, 64, 0, stream>>>(psum, pmax, Wl, bl, out);
}

// Round 3
// 799.379 us; speedup vs baseline: 1.4166x; 1.4166x over previous
//
#include <hip/hip_runtime.h>
#include <math.h>

#define N_NODES 50000
#define N_EDGES 1000000
#define HID 64

__device__ __forceinline__ float waveReduceSum64(float v) {
    #pragma unroll
    for (int o = 32; o > 0; o >>= 1) v += __shfl_xor(v, o, 64);
    return v;
}

// ---------------- node encoder: h = x @ W_node + b_node ----------------
__global__ __launch_bounds__(256) void k_node_encode(
    const float* __restrict__ x, const float* __restrict__ Wn,
    const float* __restrict__ bn, float* __restrict__ h) {
    int n = blockIdx.x * 4 + (threadIdx.x >> 6);
    int c = threadIdx.x & 63;
    if (n >= N_NODES) return;
    float acc = bn[c];
    const float* xr = x + n * 16;
    #pragma unroll
    for (int k = 0; k < 16; ++k) acc = fmaf(xr[k], Wn[k * 64 + c], acc);
    h[n * 64 + c] = acc;
}

// ---------------- edge CSR build ----------------
__global__ __launch_bounds__(256) void k_hist(const int* __restrict__ ei, int* __restrict__ cnt) {
    int i = blockIdx.x * blockDim.x + threadIdx.x;
    int stride = gridDim.x * blockDim.x;
    for (; i < N_EDGES; i += stride) atomicAdd(&cnt[ei[N_EDGES + i]], 1);
}

__global__ __launch_bounds__(256) void k_scan(const int* __restrict__ cnt,
                                              int* __restrict__ offs, int* __restrict__ cursor) {
    __shared__ int part[256];
    const int T = 256, M = N_NODES + 1;
    int t = threadIdx.x;
    int chunk = (M + T - 1) / T;
    int lo = t * chunk, hi = min(lo + chunk, M);
    int s = 0;
    for (int i = lo; i < hi; ++i) s += cnt[i];
    part[t] = s;
    __syncthreads();
    for (int d = 1; d < T; d <<= 1) {
        int v = (t >= d) ? part[t - d] : 0;
        __syncthreads();
        part[t] += v;
        __syncthreads();
    }
    int run = (t == 0) ? 0 : part[t - 1];
    for (int i = lo; i < hi; ++i) {
        offs[i] = run;
        if (i < N_NODES) cursor[i] = run;
        run += cnt[i];
    }
}

__global__ __launch_bounds__(256) void k_scatter(
    const int* __restrict__ ei, const float* __restrict__ eattr,
    int* __restrict__ cursor, int* __restrict__ s_src, float* __restrict__ s_ea) {
    int i = blockIdx.x * blockDim.x + threadIdx.x;
    int stride = gridDim.x * blockDim.x;
    for (; i < N_EDGES; i += stride) {
        int d = ei[N_EDGES + i];
        int p = atomicAdd(&cursor[d], 1);
        s_src[p] = ei[i];
        s_ea[p] = eattr[i];
    }
}

// ---------------- z = relu(LN(h, g, b)) (64 channels, one wave/node) ----------------
__global__ __launch_bounds__(256) void k_ln_relu(
    const float* __restrict__ h, const float* __restrict__ g,
    const float* __restrict__ b, float* __restrict__ z) {
    int wid = (blockIdx.x * blockDim.x + threadIdx.x) >> 6;
    int lane = threadIdx.x & 63;
    if (wid >= N_NODES) return;
    float v = h[wid * 64 + lane];
    float mu = waveReduceSum64(v) * (1.f / 64.f);
    float d = v - mu;
    float var = waveReduceSum64(d * d) * (1.f / 64.f);
    float zz = d * rsqrtf(var + 1e-5f) * g[lane] + b[lane];
    z[wid * 64 + lane] = fmaxf(zz, 0.f);
}

// ---------------- softmax aggregation, online, one wave per dst node ----------------
__global__ __launch_bounds__(256) void k_agg(
    const float* __restrict__ z, const int* __restrict__ offs,
    const int* __restrict__ s_src, const float* __restrict__ s_ea,
    const float* __restrict__ We, const float* __restrict__ be,
    const float* __restrict__ t, int layer, float* __restrict__ agg) {
    int wid = (blockIdx.x * blockDim.x + threadIdx.x) >> 6;
    int lane = threadIdx.x & 63;
    if (wid >= N_NODES) return;
    int beg = offs[wid], end = offs[wid + 1];
    float we = We[lane], bev = be[lane];
    float tl = t[layer];
    float m = -INFINITY, s = 0.f, num = 0.f;
    int i = beg;
    // 2-edge unroll: halves the sequential (max,exp,fma) accumulator chain
    for (; i + 1 < end; i += 2) {
        int sj0 = s_src[i], sj1 = s_src[i + 1];
        float ea0 = s_ea[i], ea1 = s_ea[i + 1];
        float msg0 = fmaxf(z[sj0 * 64 + lane] + fmaf(ea0, we, bev), 0.f) + 1e-7f;
        float msg1 = fmaxf(z[sj1 * 64 + lane] + fmaf(ea1, we, bev), 0.f) + 1e-7f;
        float lg0 = msg0 * tl, lg1 = msg1 * tl;
        float mn = fmaxf(m, fmaxf(lg0, lg1));
        float corr = __expf(m - mn);
        float p0 = __expf(lg0 - mn);
        float p1 = __expf(lg1 - mn);
        s = fmaf(s, corr, p0 + p1);
        num = fmaf(num, corr, fmaf(p0, msg0, p1 * msg1));
        m = mn;
    }
    if (i < end) {
        int sj = s_src[i];
        float ea = s_ea[i];
        float msg = fmaxf(z[sj * 64 + lane] + fmaf(ea, we, bev), 0.f) + 1e-7f;
        float lg = msg * tl;
        float mn = fmaxf(m, lg);
        float corr = __expf(m - mn);
        float p = __expf(lg - mn);
        s = fmaf(s, corr, p);
        num = fmaf(num, corr, p * msg);
        m = mn;
    }
    agg[wid * 64 + lane] = num / (s + 1e-16f);
}

// ---------------- fused MLP: h' = (agg+z)@W1+b1 -> LN -> relu -> @W2+b2 (+res) ----------------
// Persistent blocks: 512 threads (8 waves), grid-stride over node-groups of 8.
// Activations cross-lane via broadcast ds_read_b128 from a per-wave LDS stash
// (4 scalars/LDS-op) instead of per-scalar shuffles; weight pairs via ds_read_b64.
__global__ __launch_bounds__(512, 2) void k_mlp(
    const float* __restrict__ agg, const float* __restrict__ z,
    float* __restrict__ h, const float* __restrict__ W1, const float* __restrict__ b1,
    const float* __restrict__ g1, const float* __restrict__ be1,
    const float* __restrict__ W2, const float* __restrict__ b2, int addres) {
    __shared__ float w1p[64 * 128];       // [c][lane][2] = {W1[c][lane], W1[c][64+lane]}
    __shared__ float w2p[64 * 128];       // [j][lane][2] = {W2[j][lane], W2[j+64][lane]}
    __shared__ float stash[8][8 * 128];   // per-wave: v then u

    for (int i = threadIdx.x; i < 8192; i += 512) {
        int c = i >> 7;
        int r = i & 127;
        int ln = r >> 1, hf = r & 1;
        w1p[i] = W1[c * 128 + hf * 64 + ln];
        w2p[i] = W2[(c + hf * 64) * 64 + ln];
    }
    __syncthreads();

    int lane = threadIdx.x & 63;
    int wave = threadIdx.x >> 6;
    float* myst = stash[wave];
    float b1a = b1[lane], b1b = b1[64 + lane];
    float g1a = g1[lane], g1b = g1[64 + lane];
    float e1a = be1[lane], e1b = be1[64 + lane];
    float b2v = b2[lane];
    const int NG = N_NODES / 8;           // 6250
    const int WSTRIDE = 256 * 8;          // total waves

    for (int wid = blockIdx.x * 8 + wave; wid < NG; wid += WSTRIDE) {
        int n0 = wid * 8;
        // load v = agg + z, stash to LDS [k][64]
        #pragma unroll
        for (int k = 0; k < 8; ++k) {
            float v = agg[(n0 + k) * 64 + lane] + z[(n0 + k) * 64 + lane];
            myst[k * 64 + lane] = v;
        }
        float u0[8], u1[8];
        #pragma unroll
        for (int k = 0; k < 8; ++k) { u0[k] = b1a; u1[k] = b1b; }
        // u = v @ W1 : broadcast-read 4 c's per b128
        for (int cg = 0; cg < 64; cg += 4) {
            float4 vv[8];
            #pragma unroll
            for (int k = 0; k < 8; ++k) vv[k] = *(const float4*)&myst[k * 64 + cg];
            #pragma unroll
            for (int cc = 0; cc < 4; ++cc) {
                float2 w = *(const float2*)&w1p[(cg + cc) * 128 + lane * 2];
                #pragma unroll
                for (int k = 0; k < 8; ++k) {
                    float vc = ((const float*)&vv[k])[cc];
                    u0[k] = fmaf(vc, w.x, u0[k]);
                    u1[k] = fmaf(vc, w.y, u1[k]);
                }
            }
        }
        // LN(128) + relu, stash u to LDS [k][128]
        #pragma unroll
        for (int k = 0; k < 8; ++k) {
            float mu = waveReduceSum64(u0[k] + u1[k]) * (1.f / 128.f);
            float d0 = u0[k] - mu, d1 = u1[k] - mu;
            float var = waveReduceSum64(d0 * d0 + d1 * d1) * (1.f / 128.f);
            float rs = rsqrtf(var + 1e-5f);
            u0[k] = fmaxf(fmaf(d0 * rs, g1a, e1a), 0.f);
            u1[k] = fmaxf(fmaf(d1 * rs, g1b, e1b), 0.f);
        }
        #pragma unroll
        for (int k = 0; k < 8; ++k) {
            myst[k * 128 + lane] = u0[k];
            myst[k * 128 + 64 + lane] = u1[k];
        }
        // o = relu(LN(u)) @ W2
        float o[8];
        #pragma unroll
        for (int k = 0; k < 8; ++k) o[k] = b2v;
        for (int jg = 0; jg < 64; jg += 4) {
            float4 uL[8], uH[8];
            #pragma unroll
            for (int k = 0; k < 8; ++k) {
                uL[k] = *(const float4*)&myst[k * 128 + jg];
                uH[k] = *(const float4*)&myst[k * 128 + 64 + jg];
            }
            #pragma unroll
            for (int jj = 0; jj < 4; ++jj) {
                float2 w = *(const float2*)&w2p[(jg + jj) * 128 + lane * 2];
                #pragma unroll
                for (int k = 0; k < 8; ++k) {
                    float aL = ((const float*)&uL[k])[jj];
                    float aH = ((const float*)&uH[k])[jj];
                    o[k] = fmaf(aL, w.x, fmaf(aH, w.y, o[k]));
                }
            }
        }
        #pragma unroll
        for (int k = 0; k < 8; ++k) {
            int n = n0 + k;
            float r = addres ? (h[n * 64 + lane] + o[k]) : o[k];
            h[n * 64 + lane] = r;
        }
    }
}

// ---------------- final LN/relu + global avg & max pool partials ----------------
__global__ __launch_bounds__(256) void k_pool(
    const float* __restrict__ h, const float* __restrict__ g, const float* __restrict__ b,
    float* __restrict__ psum, unsigned int* __restrict__ pmax) {
    int wid0 = (blockIdx.x * blockDim.x + threadIdx.x) >> 6;
    int lane = threadIdx.x & 63;
    int nw = (gridDim.x * blockDim.x) >> 6;
    float ga = g[lane], ba = b[lane];
    float lsum = 0.f, lmax = 0.f;
    for (int n = wid0; n < N_NODES; n += nw) {
        float v = h[n * 64 + lane];
        float mu = waveReduceSum64(v) * (1.f / 64.f);
        float d = v - mu;
        float var = waveReduceSum64(d * d) * (1.f / 64.f);
        float zz = fmaxf(d * rsqrtf(var + 1e-5f) * ga + ba, 0.f);
        lsum += zz;
        lmax = fmaxf(lmax, zz);
    }
    atomicAdd(&psum[lane], lsum);
    atomicMax(&pmax[lane], __float_as_uint(lmax)); // post-relu >= 0: uint order == float order
}

// ---------------- head: pool bins -> emb[64] @ W_lin + b_lin ----------------
__global__ __launch_bounds__(64) void k_head(
    const float* __restrict__ psum, const unsigned int* __restrict__ pmax,
    const float* __restrict__ Wl, const float* __restrict__ bl, float* __restrict__ out) {
    __shared__ float emb[64];
    int t = threadIdx.x;
    if (t < 32) {
        emb[t] = (psum[2 * t] + psum[2 * t + 1]) * (0.5f / (float)N_NODES);
    } else {
        int i = t - 32;
        emb[t] = fmaxf(__uint_as_float(pmax[2 * i]), __uint_as_float(pmax[2 * i + 1]));
    }
    __syncthreads();
    float acc = bl[t];
    for (int k = 0; k < 64; ++k) acc = fmaf(emb[k], Wl[k * 64 + t], acc);
    out[t] = acc;
}

extern "C" void kernel_launch(void* const* d_in, const int* in_sizes, int n_in,
                              void* d_out, int out_size, void* d_ws, size_t ws_size,
                              hipStream_t stream) {
    const float* x     = (const float*)d_in[0];
    const float* eattr = (const float*)d_in[1];
    const int*   ei    = (const int*)d_in[2];
    const float* Wn    = (const float*)d_in[3];
    const float* bn    = (const float*)d_in[4];
    const float* We    = (const float*)d_in[5];
    const float* be    = (const float*)d_in[6];
    const float* t     = (const float*)d_in[7];
    const float* W1    = (const float*)d_in[8];
    const float* b1    = (const float*)d_in[9];
    const float* lg    = (const float*)d_in[10];
    const float* lb    = (const float*)d_in[11];
    const float* W2    = (const float*)d_in[12];
    const float* b2    = (const float*)d_in[13];
    const float* ng    = (const float*)d_in[14];
    const float* nb    = (const float*)d_in[15];
    const float* Wl    = (const float*)d_in[16];
    const float* bl    = (const float*)d_in[17];
    float* out = (float*)d_out;

    char* p = (char*)d_ws;
    float* h   = (float*)p; p += (size_t)N_NODES * 64 * 4;
    float* z   = (float*)p; p += (size_t)N_NODES * 64 * 4;
    float* agg = (float*)p; p += (size_t)N_NODES * 64 * 4;
    int* s_src = (int*)p;   p += (size_t)N_EDGES * 4;
    float* s_ea = (float*)p; p += (size_t)N_EDGES * 4;
    int* cnt    = (int*)p;  p += (size_t)(N_NODES + 4) * 4;
    int* offs   = (int*)p;  p += (size_t)(N_NODES + 4) * 4;
    int* cursor = (int*)p;  p += (size_t)(N_NODES + 4) * 4;
    float* psum = (float*)p; p += 64 * 4;
    unsigned int* pmax = (unsigned int*)p; p += 64 * 4;

    hipMemsetAsync(cnt, 0, (N_NODES + 1) * sizeof(int), stream);
    hipMemsetAsync(psum, 0, 64 * sizeof(float), stream);
    hipMemsetAsync(pmax, 0, 64 * sizeof(unsigned int), stream);

    k_node_encode<<<(N_NODES + 3) / 4, 256, 0, stream>>>(x, Wn, bn, h);
    k_hist<<<1024, 256, 0, stream>>>(ei, cnt);
    k_scan<<<1, 256, 0, stream>>>(cnt, offs, cursor);
    k_scatter<<<1024, 256, 0, stream>>>(ei, eattr, cursor, s_src, s_ea);

    for (int i = 0; i < 3; ++i) {
        const float* zp;
        if (i > 0) {
            k_ln_relu<<<(N_NODES + 3) / 4, 256, 0, stream>>>(h, ng + i * 64, nb + i * 64, z);
            zp = z;
        } else {
            zp = h;
        }
        k_agg<<<(N_NODES + 3) / 4, 256, 0, stream>>>(zp, offs, s_src, s_ea, We, be, t, i, agg);
        k_mlp<<<256, 512, 0, stream>>>(
            agg, zp, h, W1 + (size_t)i * 64 * 128, b1 + i * 128, lg + i * 128, lb + i * 128,
            W2 + (size_t)i * 128 * 64, b2 + i * 64, i > 0);
    }

    k_pool<<<256, 256, 0, stream>>>(h, ng, nb, psum, pmax);
    k_head<<<1, 64, 0, stream>>>(psum, pmax, Wl, bl, out);
}

// Round 4
// 678.623 us; speedup vs baseline: 1.6687x; 1.1779x over previous
//
#include <hip/hip_runtime.h>
#include <math.h>

#define N_NODES 50000
#define N_EDGES 1000000
#define HID 64
#define SCAN_NB ((N_NODES + 1 + 255) / 256)   // 196 blocks over N_NODES+1 counters

__device__ __forceinline__ float waveReduceSum64(float v) {
    #pragma unroll
    for (int o = 32; o > 0; o >>= 1) v += __shfl_xor(v, o, 64);
    return v;
}

// ---------------- node encoder: h = x @ W_node + b_node ----------------
__global__ __launch_bounds__(256) void k_node_encode(
    const float* __restrict__ x, const float* __restrict__ Wn,
    const float* __restrict__ bn, float* __restrict__ h) {
    int n = blockIdx.x * 4 + (threadIdx.x >> 6);
    int c = threadIdx.x & 63;
    if (n >= N_NODES) return;
    float acc = bn[c];
    const float* xr = x + n * 16;
    #pragma unroll
    for (int k = 0; k < 16; ++k) acc = fmaf(xr[k], Wn[k * 64 + c], acc);
    h[n * 64 + c] = acc;
}

// ---------------- edge CSR build ----------------
__global__ __launch_bounds__(256) void k_hist(const int* __restrict__ ei, int* __restrict__ cnt) {
    int i = blockIdx.x * blockDim.x + threadIdx.x;
    int stride = gridDim.x * blockDim.x;
    for (; i < N_EDGES; i += stride) atomicAdd(&cnt[ei[N_EDGES + i]], 1);
}

// 3-phase hierarchical exclusive scan over cnt[0..N_NODES] -> offs, cursor
__global__ __launch_bounds__(256) void k_scan1(const int* __restrict__ cnt,
                                               int* __restrict__ inc, int* __restrict__ bsum) {
    __shared__ int sh[256];
    int gi = blockIdx.x * 256 + threadIdx.x;
    int v = (gi < N_NODES + 1) ? cnt[gi] : 0;
    sh[threadIdx.x] = v;
    __syncthreads();
    #pragma unroll
    for (int d = 1; d < 256; d <<= 1) {
        int t = (threadIdx.x >= d) ? sh[threadIdx.x - d] : 0;
        __syncthreads();
        sh[threadIdx.x] += t;
        __syncthreads();
    }
    if (gi < N_NODES + 1) inc[gi] = sh[threadIdx.x];
    if (threadIdx.x == 255) bsum[blockIdx.x] = sh[255];
}

__global__ __launch_bounds__(256) void k_scan2(int* __restrict__ bsum) {
    __shared__ int sh[256];
    int t = threadIdx.x;
    sh[t] = (t < SCAN_NB) ? bsum[t] : 0;
    __syncthreads();
    #pragma unroll
    for (int d = 1; d < 256; d <<= 1) {
        int v = (t >= d) ? sh[t - d] : 0;
        __syncthreads();
        sh[t] += v;
        __syncthreads();
    }
    if (t < SCAN_NB) bsum[t] = (t == 0) ? 0 : sh[t - 1];   // exclusive block prefix
}

__global__ __launch_bounds__(256) void k_scan3(const int* __restrict__ inc,
                                               const int* __restrict__ cnt,
                                               const int* __restrict__ bsum,
                                               int* __restrict__ offs, int* __restrict__ cursor) {
    int gi = blockIdx.x * 256 + threadIdx.x;
    if (gi < N_NODES + 1) {
        int e = bsum[blockIdx.x] + inc[gi] - cnt[gi];      // exclusive prefix
        offs[gi] = e;
        if (gi < N_NODES) cursor[gi] = e;
    }
}

__global__ __launch_bounds__(256) void k_scatter(
    const int* __restrict__ ei, const float* __restrict__ eattr,
    int* __restrict__ cursor, int* __restrict__ s_src, float* __restrict__ s_ea) {
    int i = blockIdx.x * blockDim.x + threadIdx.x;
    int stride = gridDim.x * blockDim.x;
    for (; i < N_EDGES; i += stride) {
        int d = ei[N_EDGES + i];
        int p = atomicAdd(&cursor[d], 1);
        s_src[p] = ei[i];
        s_ea[p] = eattr[i];
    }
}

// ---------------- z = relu(LN(h, g, b)) (64 channels, one wave/node) ----------------
__global__ __launch_bounds__(256) void k_ln_relu(
    const float* __restrict__ h, const float* __restrict__ g,
    const float* __restrict__ b, float* __restrict__ z) {
    int wid = (blockIdx.x * blockDim.x + threadIdx.x) >> 6;
    int lane = threadIdx.x & 63;
    if (wid >= N_NODES) return;
    float v = h[wid * 64 + lane];
    float mu = waveReduceSum64(v) * (1.f / 64.f);
    float d = v - mu;
    float var = waveReduceSum64(d * d) * (1.f / 64.f);
    float zz = d * rsqrtf(var + 1e-5f) * g[lane] + b[lane];
    z[wid * 64 + lane] = fmaxf(zz, 0.f);
}

// ---------------- softmax aggregation, online, one wave per dst node ----------------
__global__ __launch_bounds__(256) void k_agg(
    const float* __restrict__ z, const int* __restrict__ offs,
    const int* __restrict__ s_src, const float* __restrict__ s_ea,
    const float* __restrict__ We, const float* __restrict__ be,
    const float* __restrict__ t, int layer, float* __restrict__ agg) {
    int wid = (blockIdx.x * blockDim.x + threadIdx.x) >> 6;
    int lane = threadIdx.x & 63;
    if (wid >= N_NODES) return;
    int beg = offs[wid], end = offs[wid + 1];
    float we = We[lane], bev = be[lane];
    float tl = t[layer];
    float m = -INFINITY, s = 0.f, num = 0.f;
    int i = beg;
    for (; i + 1 < end; i += 2) {
        int sj0 = s_src[i], sj1 = s_src[i + 1];
        float ea0 = s_ea[i], ea1 = s_ea[i + 1];
        float msg0 = fmaxf(z[sj0 * 64 + lane] + fmaf(ea0, we, bev), 0.f) + 1e-7f;
        float msg1 = fmaxf(z[sj1 * 64 + lane] + fmaf(ea1, we, bev), 0.f) + 1e-7f;
        float lg0 = msg0 * tl, lg1 = msg1 * tl;
        float mn = fmaxf(m, fmaxf(lg0, lg1));
        float corr = __expf(m - mn);
        float p0 = __expf(lg0 - mn);
        float p1 = __expf(lg1 - mn);
        s = fmaf(s, corr, p0 + p1);
        num = fmaf(num, corr, fmaf(p0, msg0, p1 * msg1));
        m = mn;
    }
    if (i < end) {
        int sj = s_src[i];
        float ea = s_ea[i];
        float msg = fmaxf(z[sj * 64 + lane] + fmaf(ea, we, bev), 0.f) + 1e-7f;
        float lg = msg * tl;
        float mn = fmaxf(m, lg);
        float corr = __expf(m - mn);
        float p = __expf(lg - mn);
        s = fmaf(s, corr, p);
        num = fmaf(num, corr, p * msg);
        m = mn;
    }
    agg[wid * 64 + lane] = num / (s + 1e-16f);
}

// ---------------- fused MLP (persistent, broadcast ds_read_b128 GEMMs) ----------------
__global__ __launch_bounds__(512, 2) void k_mlp(
    const float* __restrict__ agg, const float* __restrict__ z,
    float* __restrict__ h, const float* __restrict__ W1, const float* __restrict__ b1,
    const float* __restrict__ g1, const float* __restrict__ be1,
    const float* __restrict__ W2, const float* __restrict__ b2, int addres) {
    __shared__ float w1p[64 * 128];       // [c][lane][2] = {W1[c][lane], W1[c][64+lane]}
    __shared__ float w2p[64 * 128];       // [j][lane][2] = {W2[j][lane], W2[j+64][lane]}
    __shared__ float stash[8][8 * 128];   // per-wave: v then u

    for (int i = threadIdx.x; i < 8192; i += 512) {
        int c = i >> 7;
        int r = i & 127;
        int ln = r >> 1, hf = r & 1;
        w1p[i] = W1[c * 128 + hf * 64 + ln];
        w2p[i] = W2[(c + hf * 64) * 64 + ln];
    }
    __syncthreads();

    int lane = threadIdx.x & 63;
    int wave = threadIdx.x >> 6;
    float* myst = stash[wave];
    float b1a = b1[lane], b1b = b1[64 + lane];
    float g1a = g1[lane], g1b = g1[64 + lane];
    float e1a = be1[lane], e1b = be1[64 + lane];
    float b2v = b2[lane];
    const int NG = N_NODES / 8;           // 6250
    const int WSTRIDE = 256 * 8;

    for (int wid = blockIdx.x * 8 + wave; wid < NG; wid += WSTRIDE) {
        int n0 = wid * 8;
        #pragma unroll
        for (int k = 0; k < 8; ++k) {
            float v = agg[(n0 + k) * 64 + lane] + z[(n0 + k) * 64 + lane];
            myst[k * 64 + lane] = v;
        }
        float u0[8], u1[8];
        #pragma unroll
        for (int k = 0; k < 8; ++k) { u0[k] = b1a; u1[k] = b1b; }
        for (int cg = 0; cg < 64; cg += 4) {
            float4 vv[8];
            #pragma unroll
            for (int k = 0; k < 8; ++k) vv[k] = *(const float4*)&myst[k * 64 + cg];
            #pragma unroll
            for (int cc = 0; cc < 4; ++cc) {
                float2 w = *(const float2*)&w1p[(cg + cc) * 128 + lane * 2];
                #pragma unroll
                for (int k = 0; k < 8; ++k) {
                    float vc = ((const float*)&vv[k])[cc];
                    u0[k] = fmaf(vc, w.x, u0[k]);
                    u1[k] = fmaf(vc, w.y, u1[k]);
                }
            }
        }
        #pragma unroll
        for (int k = 0; k < 8; ++k) {
            float mu = waveReduceSum64(u0[k] + u1[k]) * (1.f / 128.f);
            float d0 = u0[k] - mu, d1 = u1[k] - mu;
            float var = waveReduceSum64(d0 * d0 + d1 * d1) * (1.f / 128.f);
            float rs = rsqrtf(var + 1e-5f);
            u0[k] = fmaxf(fmaf(d0 * rs, g1a, e1a), 0.f);
            u1[k] = fmaxf(fmaf(d1 * rs, g1b, e1b), 0.f);
        }
        #pragma unroll
        for (int k = 0; k < 8; ++k) {
            myst[k * 128 + lane] = u0[k];
            myst[k * 128 + 64 + lane] = u1[k];
        }
        float o[8];
        #pragma unroll
        for (int k = 0; k < 8; ++k) o[k] = b2v;
        for (int jg = 0; jg < 64; jg += 4) {
            float4 uL[8], uH[8];
            #pragma unroll
            for (int k = 0; k < 8; ++k) {
                uL[k] = *(const float4*)&myst[k * 128 + jg];
                uH[k] = *(const float4*)&myst[k * 128 + 64 + jg];
            }
            #pragma unroll
            for (int jj = 0; jj < 4; ++jj) {
                float2 w = *(const float2*)&w2p[(jg + jj) * 128 + lane * 2];
                #pragma unroll
                for (int k = 0; k < 8; ++k) {
                    float aL = ((const float*)&uL[k])[jj];
                    float aH = ((const float*)&uH[k])[jj];
                    o[k] = fmaf(aL, w.x, fmaf(aH, w.y, o[k]));
                }
            }
        }
        #pragma unroll
        for (int k = 0; k < 8; ++k) {
            int n = n0 + k;
            float r = addres ? (h[n * 64 + lane] + o[k]) : o[k];
            h[n * 64 + lane] = r;
        }
    }
}

// ---------------- final LN/relu + global avg & max pool partials ----------------
__global__ __launch_bounds__(256) void k_pool(
    const float* __restrict__ h, const float* __restrict__ g, const float* __restrict__ b,
    float* __restrict__ psum, unsigned int* __restrict__ pmax) {
    int wid0 = (blockIdx.x * blockDim.x + threadIdx.x) >> 6;
    int lane = threadIdx.x & 63;
    int nw = (gridDim.x * blockDim.x) >> 6;
    float ga = g[lane], ba = b[lane];
    float lsum = 0.f, lmax = 0.f;
    for (int n = wid0; n < N_NODES; n += nw) {
        float v = h[n * 64 + lane];
        float mu = waveReduceSum64(v) * (1.f / 64.f);
        float d = v - mu;
        float var = waveReduceSum64(d * d) * (1.f / 64.f);
        float zz = fmaxf(d * rsqrtf(var + 1e-5f) * ga + ba, 0.f);
        lsum += zz;
        lmax = fmaxf(lmax, zz);
    }
    atomicAdd(&psum[lane], lsum);
    atomicMax(&pmax[lane], __float_as_uint(lmax));
}

// ---------------- head ----------------
__global__ __launch_bounds__(64) void k_head(
    const float* __restrict__ psum, const unsigned int* __restrict__ pmax,
    const float* __restrict__ Wl, const float* __restrict__ bl, float* __restrict__ out) {
    __shared__ float emb[64];
    int t = threadIdx.x;
    if (t < 32) {
        emb[t] = (psum[2 * t] + psum[2 * t + 1]) * (0.5f / (float)N_NODES);
    } else {
        int i = t - 32;
        emb[t] = fmaxf(__uint_as_float(pmax[2 * i]), __uint_as_float(pmax[2 * i + 1]));
    }
    __syncthreads();
    float acc = bl[t];
    for (int k = 0; k < 64; ++k) acc = fmaf(emb[k], Wl[k * 64 + t], acc);
    out[t] = acc;
}

extern "C" void kernel_launch(void* const* d_in, const int* in_sizes, int n_in,
                              void* d_out, int out_size, void* d_ws, size_t ws_size,
                              hipStream_t stream) {
    const float* x     = (const float*)d_in[0];
    const float* eattr = (const float*)d_in[1];
    const int*   ei    = (const int*)d_in[2];
    const float* Wn    = (const float*)d_in[3];
    const float* bn    = (const float*)d_in[4];
    const float* We    = (const float*)d_in[5];
    const float* be    = (const float*)d_in[6];
    const float* t     = (const float*)d_in[7];
    const float* W1    = (const float*)d_in[8];
    const float* b1    = (const float*)d_in[9];
    const float* lg    = (const float*)d_in[10];
    const float* lb    = (const float*)d_in[11];
    const float* W2    = (const float*)d_in[12];
    const float* b2    = (const float*)d_in[13];
    const float* ng    = (const float*)d_in[14];
    const float* nb    = (const float*)d_in[15];
    const float* Wl    = (const float*)d_in[16];
    const float* bl    = (const float*)d_in[17];
    float* out = (float*)d_out;

    char* p = (char*)d_ws;
    float* h   = (float*)p; p += (size_t)N_NODES * 64 * 4;
    float* z   = (float*)p; p += (size_t)N_NODES * 64 * 4;
    float* agg = (float*)p; p += (size_t)N_NODES * 64 * 4;
    int* s_src = (int*)p;   p += (size_t)N_EDGES * 4;
    float* s_ea = (float*)p; p += (size_t)N_EDGES * 4;
    int* cnt    = (int*)p;  p += (size_t)(N_NODES + 4) * 4;
    int* offs   = (int*)p;  p += (size_t)(N_NODES + 4) * 4;
    int* cursor = (int*)p;  p += (size_t)(N_NODES + 4) * 4;
    int* inc    = (int*)p;  p += (size_t)(N_NODES + 4) * 4;
    int* bsum   = (int*)p;  p += (size_t)256 * 4;
    float* psum = (float*)p; p += 64 * 4;
    unsigned int* pmax = (unsigned int*)p; p += 64 * 4;

    hipMemsetAsync(cnt, 0, (N_NODES + 1) * sizeof(int), stream);
    hipMemsetAsync(psum, 0, 64 * sizeof(float), stream);
    hipMemsetAsync(pmax, 0, 64 * sizeof(unsigned int), stream);

    k_node_encode<<<(N_NODES + 3) / 4, 256, 0, stream>>>(x, Wn, bn, h);
    k_hist<<<1024, 256, 0, stream>>>(ei, cnt);
    k_scan1<<<SCAN_NB, 256, 0, stream>>>(cnt, inc, bsum);
    k_scan2<<<1, 256, 0, stream>>>(bsum);
    k_scan3<<<SCAN_NB, 256, 0, stream>>>(inc, cnt, bsum, offs, cursor);
    k_scatter<<<1024, 256, 0, stream>>>(ei, eattr, cursor, s_src, s_ea);

    for (int i = 0; i < 3; ++i) {
        const float* zp;
        if (i > 0) {
            k_ln_relu<<<(N_NODES + 3) / 4, 256, 0, stream>>>(h, ng + i * 64, nb + i * 64, z);
            zp = z;
        } else {
            zp = h;
        }
        k_agg<<<(N_NODES + 3) / 4, 256, 0, stream>>>(zp, offs, s_src, s_ea, We, be, t, i, agg);
        k_mlp<<<256, 512, 0, stream>>>(
            agg, zp, h, W1 + (size_t)i * 64 * 128, b1 + i * 128, lg + i * 128, lb + i * 128,
            W2 + (size_t)i * 128 * 64, b2 + i * 64, i > 0);
    }

    k_pool<<<256, 256, 0, stream>>>(h, ng, nb, psum, pmax);
    k_head<<<1, 64, 0, stream>>>(psum, pmax, Wl, bl, out);
}

// Round 5
// 675.360 us; speedup vs baseline: 1.6767x; 1.0048x over previous
//
#include <hip/hip_runtime.h>
#include <math.h>

#define N_NODES 50000
#define N_EDGES 1000000
#define HID 64
#define SCAN_NB ((N_NODES + 1 + 255) / 256)   // 196 blocks over N_NODES+1 counters

__device__ __forceinline__ float waveReduceSum64(float v) {
    #pragma unroll
    for (int o = 32; o > 0; o >>= 1) v += __shfl_xor(v, o, 64);
    return v;
}

// ---------------- node encoder: h = x @ W_node + b_node ----------------
__global__ __launch_bounds__(256) void k_node_encode(
    const float* __restrict__ x, const float* __restrict__ Wn,
    const float* __restrict__ bn, float* __restrict__ h) {
    int n = blockIdx.x * 4 + (threadIdx.x >> 6);
    int c = threadIdx.x & 63;
    if (n >= N_NODES) return;
    float acc = bn[c];
    const float* xr = x + n * 16;
    #pragma unroll
    for (int k = 0; k < 16; ++k) acc = fmaf(xr[k], Wn[k * 64 + c], acc);
    h[n * 64 + c] = acc;
}

// ---------------- edge CSR build ----------------
__global__ __launch_bounds__(256) void k_hist(const int* __restrict__ ei, int* __restrict__ cnt) {
    int i = blockIdx.x * blockDim.x + threadIdx.x;
    int stride = gridDim.x * blockDim.x;
    for (; i < N_EDGES; i += stride) atomicAdd(&cnt[ei[N_EDGES + i]], 1);
}

// 3-phase hierarchical exclusive scan over cnt[0..N_NODES] -> offs, cursor
__global__ __launch_bounds__(256) void k_scan1(const int* __restrict__ cnt,
                                               int* __restrict__ inc, int* __restrict__ bsum) {
    __shared__ int sh[256];
    int gi = blockIdx.x * 256 + threadIdx.x;
    int v = (gi < N_NODES + 1) ? cnt[gi] : 0;
    sh[threadIdx.x] = v;
    __syncthreads();
    #pragma unroll
    for (int d = 1; d < 256; d <<= 1) {
        int t = (threadIdx.x >= d) ? sh[threadIdx.x - d] : 0;
        __syncthreads();
        sh[threadIdx.x] += t;
        __syncthreads();
    }
    if (gi < N_NODES + 1) inc[gi] = sh[threadIdx.x];
    if (threadIdx.x == 255) bsum[blockIdx.x] = sh[255];
}

__global__ __launch_bounds__(256) void k_scan2(int* __restrict__ bsum) {
    __shared__ int sh[256];
    int t = threadIdx.x;
    sh[t] = (t < SCAN_NB) ? bsum[t] : 0;
    __syncthreads();
    #pragma unroll
    for (int d = 1; d < 256; d <<= 1) {
        int v = (t >= d) ? sh[t - d] : 0;
        __syncthreads();
        sh[t] += v;
        __syncthreads();
    }
    if (t < SCAN_NB) bsum[t] = (t == 0) ? 0 : sh[t - 1];   // exclusive block prefix
}

__global__ __launch_bounds__(256) void k_scan3(const int* __restrict__ inc,
                                               const int* __restrict__ cnt,
                                               const int* __restrict__ bsum,
                                               int* __restrict__ offs, int* __restrict__ cursor) {
    int gi = blockIdx.x * 256 + threadIdx.x;
    if (gi < N_NODES + 1) {
        int e = bsum[blockIdx.x] + inc[gi] - cnt[gi];      // exclusive prefix
        offs[gi] = e;
        if (gi < N_NODES) cursor[gi] = e;
    }
}

// one edge per thread; packed (src, eattr) -> single 8B random store
__global__ __launch_bounds__(256) void k_scatter(
    const int* __restrict__ ei, const float* __restrict__ eattr,
    int* __restrict__ cursor, int2* __restrict__ s_pack) {
    int i = blockIdx.x * blockDim.x + threadIdx.x;
    if (i >= N_EDGES) return;
    int d = ei[N_EDGES + i];
    int p = atomicAdd(&cursor[d], 1);
    int2 pk;
    pk.x = ei[i];
    pk.y = __float_as_int(eattr[i]);
    s_pack[p] = pk;
}

// ---------------- z = relu(LN(h, g, b)) (64 channels, one wave/node) ----------------
__global__ __launch_bounds__(256) void k_ln_relu(
    const float* __restrict__ h, const float* __restrict__ g,
    const float* __restrict__ b, float* __restrict__ z) {
    int wid = (blockIdx.x * blockDim.x + threadIdx.x) >> 6;
    int lane = threadIdx.x & 63;
    if (wid >= N_NODES) return;
    float v = h[wid * 64 + lane];
    float mu = waveReduceSum64(v) * (1.f / 64.f);
    float d = v - mu;
    float var = waveReduceSum64(d * d) * (1.f / 64.f);
    float zz = d * rsqrtf(var + 1e-5f) * g[lane] + b[lane];
    z[wid * 64 + lane] = fmaxf(zz, 0.f);
}

// ---------------- softmax aggregation, online, one wave per dst node ----------------
__global__ __launch_bounds__(256) void k_agg(
    const float* __restrict__ z, const int* __restrict__ offs,
    const int2* __restrict__ s_pack,
    const float* __restrict__ We, const float* __restrict__ be,
    const float* __restrict__ t, int layer, float* __restrict__ agg) {
    int wid = (blockIdx.x * blockDim.x + threadIdx.x) >> 6;
    int lane = threadIdx.x & 63;
    if (wid >= N_NODES) return;
    int beg = offs[wid], end = offs[wid + 1];
    float we = We[lane], bev = be[lane];
    float tl = t[layer];
    float m = -INFINITY, s = 0.f, num = 0.f;
    int i = beg;
    for (; i + 1 < end; i += 2) {
        int2 p0i = s_pack[i], p1i = s_pack[i + 1];
        float ea0 = __int_as_float(p0i.y), ea1 = __int_as_float(p1i.y);
        float msg0 = fmaxf(z[p0i.x * 64 + lane] + fmaf(ea0, we, bev), 0.f) + 1e-7f;
        float msg1 = fmaxf(z[p1i.x * 64 + lane] + fmaf(ea1, we, bev), 0.f) + 1e-7f;
        float lg0 = msg0 * tl, lg1 = msg1 * tl;
        float mn = fmaxf(m, fmaxf(lg0, lg1));
        float corr = __expf(m - mn);
        float p0 = __expf(lg0 - mn);
        float p1 = __expf(lg1 - mn);
        s = fmaf(s, corr, p0 + p1);
        num = fmaf(num, corr, fmaf(p0, msg0, p1 * msg1));
        m = mn;
    }
    if (i < end) {
        int2 pk = s_pack[i];
        float ea = __int_as_float(pk.y);
        float msg = fmaxf(z[pk.x * 64 + lane] + fmaf(ea, we, bev), 0.f) + 1e-7f;
        float lg = msg * tl;
        float mn = fmaxf(m, lg);
        float corr = __expf(m - mn);
        float p = __expf(lg - mn);
        s = fmaf(s, corr, p);
        num = fmaf(num, corr, p * msg);
        m = mn;
    }
    agg[wid * 64 + lane] = num / (s + 1e-16f);
}

// ---------------- fused MLP (persistent, broadcast ds_read_b128 GEMMs) ----------------
__global__ __launch_bounds__(512, 2) void k_mlp(
    const float* __restrict__ agg, const float* __restrict__ z,
    float* __restrict__ h, const float* __restrict__ W1, const float* __restrict__ b1,
    const float* __restrict__ g1, const float* __restrict__ be1,
    const float* __restrict__ W2, const float* __restrict__ b2, int addres) {
    __shared__ float w1p[64 * 128];       // [c][lane][2] = {W1[c][lane], W1[c][64+lane]}
    __shared__ float w2p[64 * 128];       // [j][lane][2] = {W2[j][lane], W2[j+64][lane]}
    __shared__ float stash[8][8 * 128];   // per-wave: v then u

    for (int i = threadIdx.x; i < 8192; i += 512) {
        int c = i >> 7;
        int r = i & 127;
        int ln = r >> 1, hf = r & 1;
        w1p[i] = W1[c * 128 + hf * 64 + ln];
        w2p[i] = W2[(c + hf * 64) * 64 + ln];
    }
    __syncthreads();

    int lane = threadIdx.x & 63;
    int wave = threadIdx.x >> 6;
    float* myst = stash[wave];
    float b1a = b1[lane], b1b = b1[64 + lane];
    float g1a = g1[lane], g1b = g1[64 + lane];
    float e1a = be1[lane], e1b = be1[64 + lane];
    float b2v = b2[lane];
    const int NG = N_NODES / 8;           // 6250
    const int WSTRIDE = 256 * 8;

    for (int wid = blockIdx.x * 8 + wave; wid < NG; wid += WSTRIDE) {
        int n0 = wid * 8;
        #pragma unroll
        for (int k = 0; k < 8; ++k) {
            float v = agg[(n0 + k) * 64 + lane] + z[(n0 + k) * 64 + lane];
            myst[k * 64 + lane] = v;
        }
        float u0[8], u1[8];
        #pragma unroll
        for (int k = 0; k < 8; ++k) { u0[k] = b1a; u1[k] = b1b; }
        for (int cg = 0; cg < 64; cg += 4) {
            float4 vv[8];
            #pragma unroll
            for (int k = 0; k < 8; ++k) vv[k] = *(const float4*)&myst[k * 64 + cg];
            #pragma unroll
            for (int cc = 0; cc < 4; ++cc) {
                float2 w = *(const float2*)&w1p[(cg + cc) * 128 + lane * 2];
                #pragma unroll
                for (int k = 0; k < 8; ++k) {
                    float vc = ((const float*)&vv[k])[cc];
                    u0[k] = fmaf(vc, w.x, u0[k]);
                    u1[k] = fmaf(vc, w.y, u1[k]);
                }
            }
        }
        #pragma unroll
        for (int k = 0; k < 8; ++k) {
            float mu = waveReduceSum64(u0[k] + u1[k]) * (1.f / 128.f);
            float d0 = u0[k] - mu, d1 = u1[k] - mu;
            float var = waveReduceSum64(d0 * d0 + d1 * d1) * (1.f / 128.f);
            float rs = rsqrtf(var + 1e-5f);
            u0[k] = fmaxf(fmaf(d0 * rs, g1a, e1a), 0.f);
            u1[k] = fmaxf(fmaf(d1 * rs, g1b, e1b), 0.f);
        }
        #pragma unroll
        for (int k = 0; k < 8; ++k) {
            myst[k * 128 + lane] = u0[k];
            myst[k * 128 + 64 + lane] = u1[k];
        }
        float o[8];
        #pragma unroll
        for (int k = 0; k < 8; ++k) o[k] = b2v;
        for (int jg = 0; jg < 64; jg += 4) {
            float4 uL[8], uH[8];
            #pragma unroll
            for (int k = 0; k < 8; ++k) {
                uL[k] = *(const float4*)&myst[k * 128 + jg];
                uH[k] = *(const float4*)&myst[k * 128 + 64 + jg];
            }
            #pragma unroll
            for (int jj = 0; jj < 4; ++jj) {
                float2 w = *(const float2*)&w2p[(jg + jj) * 128 + lane * 2];
                #pragma unroll
                for (int k = 0; k < 8; ++k) {
                    float aL = ((const float*)&uL[k])[jj];
                    float aH = ((const float*)&uH[k])[jj];
                    o[k] = fmaf(aL, w.x, fmaf(aH, w.y, o[k]));
                }
            }
        }
        #pragma unroll
        for (int k = 0; k < 8; ++k) {
            int n = n0 + k;
            float r = addres ? (h[n * 64 + lane] + o[k]) : o[k];
            h[n * 64 + lane] = r;
        }
    }
}

// ---------------- final LN/relu + global avg & max pool partials ----------------
__global__ __launch_bounds__(256) void k_pool(
    const float* __restrict__ h, const float* __restrict__ g, const float* __restrict__ b,
    float* __restrict__ psum, unsigned int* __restrict__ pmax) {
    int wid0 = (blockIdx.x * blockDim.x + threadIdx.x) >> 6;
    int lane = threadIdx.x & 63;
    int nw = (gridDim.x * blockDim.x) >> 6;
    float ga = g[lane], ba = b[lane];
    float lsum = 0.f, lmax = 0.f;
    for (int n = wid0; n < N_NODES; n += nw) {
        float v = h[n * 64 + lane];
        float mu = waveReduceSum64(v) * (1.f / 64.f);
        float d = v - mu;
        float var = waveReduceSum64(d * d) * (1.f / 64.f);
        float zz = fmaxf(d * rsqrtf(var + 1e-5f) * ga + ba, 0.f);
        lsum += zz;
        lmax = fmaxf(lmax, zz);
    }
    atomicAdd(&psum[lane], lsum);
    atomicMax(&pmax[lane], __float_as_uint(lmax));
}

// ---------------- head ----------------
__global__ __launch_bounds__(64) void k_head(
    const float* __restrict__ psum, const unsigned int* __restrict__ pmax,
    const float* __restrict__ Wl, const float* __restrict__ bl, float* __restrict__ out) {
    __shared__ float emb[64];
    int t = threadIdx.x;
    if (t < 32) {
        emb[t] = (psum[2 * t] + psum[2 * t + 1]) * (0.5f / (float)N_NODES);
    } else {
        int i = t - 32;
        emb[t] = fmaxf(__uint_as_float(pmax[2 * i]), __uint_as_float(pmax[2 * i + 1]));
    }
    __syncthreads();
    float acc = bl[t];
    for (int k = 0; k < 64; ++k) acc = fmaf(emb[k], Wl[k * 64 + t], acc);
    out[t] = acc;
}

extern "C" void kernel_launch(void* const* d_in, const int* in_sizes, int n_in,
                              void* d_out, int out_size, void* d_ws, size_t ws_size,
                              hipStream_t stream) {
    const float* x     = (const float*)d_in[0];
    const float* eattr = (const float*)d_in[1];
    const int*   ei    = (const int*)d_in[2];
    const float* Wn    = (const float*)d_in[3];
    const float* bn    = (const float*)d_in[4];
    const float* We    = (const float*)d_in[5];
    const float* be    = (const float*)d_in[6];
    const float* t     = (const float*)d_in[7];
    const float* W1    = (const float*)d_in[8];
    const float* b1    = (const float*)d_in[9];
    const float* lg    = (const float*)d_in[10];
    const float* lb    = (const float*)d_in[11];
    const float* W2    = (const float*)d_in[12];
    const float* b2    = (const float*)d_in[13];
    const float* ng    = (const float*)d_in[14];
    const float* nb    = (const float*)d_in[15];
    const float* Wl    = (const float*)d_in[16];
    const float* bl    = (const float*)d_in[17];
    float* out = (float*)d_out;

    char* p = (char*)d_ws;
    float* h   = (float*)p; p += (size_t)N_NODES * 64 * 4;
    float* z   = (float*)p; p += (size_t)N_NODES * 64 * 4;
    float* agg = (float*)p; p += (size_t)N_NODES * 64 * 4;
    int2* s_pack = (int2*)p; p += (size_t)N_EDGES * 8;
    int* cnt    = (int*)p;  p += (size_t)(N_NODES + 4) * 4;
    int* offs   = (int*)p;  p += (size_t)(N_NODES + 4) * 4;
    int* cursor = (int*)p;  p += (size_t)(N_NODES + 4) * 4;
    int* inc    = (int*)p;  p += (size_t)(N_NODES + 4) * 4;
    int* bsum   = (int*)p;  p += (size_t)256 * 4;
    float* psum = (float*)p; p += 64 * 4;
    unsigned int* pmax = (unsigned int*)p; p += 64 * 4;

    hipMemsetAsync(cnt, 0, (N_NODES + 1) * sizeof(int), stream);
    hipMemsetAsync(psum, 0, 64 * sizeof(float), stream);
    hipMemsetAsync(pmax, 0, 64 * sizeof(unsigned int), stream);

    k_node_encode<<<(N_NODES + 3) / 4, 256, 0, stream>>>(x, Wn, bn, h);
    k_hist<<<1024, 256, 0, stream>>>(ei, cnt);
    k_scan1<<<SCAN_NB, 256, 0, stream>>>(cnt, inc, bsum);
    k_scan2<<<1, 256, 0, stream>>>(bsum);
    k_scan3<<<SCAN_NB, 256, 0, stream>>>(inc, cnt, bsum, offs, cursor);
    k_scatter<<<(N_EDGES + 255) / 256, 256, 0, stream>>>(ei, eattr, cursor, s_pack);

    for (int i = 0; i < 3; ++i) {
        const float* zp;
        if (i > 0) {
            k_ln_relu<<<(N_NODES + 3) / 4, 256, 0, stream>>>(h, ng + i * 64, nb + i * 64, z);
            zp = z;
        } else {
            zp = h;
        }
        k_agg<<<(N_NODES + 3) / 4, 256, 0, stream>>>(zp, offs, s_pack, We, be, t, i, agg);
        k_mlp<<<256, 512, 0, stream>>>(
            agg, zp, h, W1 + (size_t)i * 64 * 128, b1 + i * 128, lg + i * 128, lb + i * 128,
            W2 + (size_t)i * 128 * 64, b2 + i * 64, i > 0);
    }

    k_pool<<<256, 256, 0, stream>>>(h, ng, nb, psum, pmax);
    k_head<<<1, 64, 0, stream>>>(psum, pmax, Wl, bl, out);
}

// Round 6
// 556.674 us; speedup vs baseline: 2.0342x; 1.2132x over previous
//
#include <hip/hip_runtime.h>
#include <math.h>

#define N_NODES 50000
#define N_EDGES 1000000
#define HID 64
#define SCAN_NB ((N_NODES + 1 + 255) / 256)

typedef __attribute__((ext_vector_type(8))) short short8;   // 8 bf16 = 4 VGPRs
typedef __attribute__((ext_vector_type(4))) float f32x4;

__device__ __forceinline__ unsigned short f2bf(float x) {   // RNE float->bf16
    unsigned u = __float_as_uint(x);
    u += 0x7FFFu + ((u >> 16) & 1u);
    return (unsigned short)(u >> 16);
}

__device__ __forceinline__ float waveReduceSum64(float v) {
    #pragma unroll
    for (int o = 32; o > 0; o >>= 1) v += __shfl_xor(v, o, 64);
    return v;
}

// ---------------- node encoder: h = x @ W_node + b_node ----------------
__global__ __launch_bounds__(256) void k_node_encode(
    const float* __restrict__ x, const float* __restrict__ Wn,
    const float* __restrict__ bn, float* __restrict__ h) {
    int n = blockIdx.x * 4 + (threadIdx.x >> 6);
    int c = threadIdx.x & 63;
    if (n >= N_NODES) return;
    float acc = bn[c];
    const float* xr = x + n * 16;
    #pragma unroll
    for (int k = 0; k < 16; ++k) acc = fmaf(xr[k], Wn[k * 64 + c], acc);
    h[n * 64 + c] = acc;
}

// ---------------- edge CSR build ----------------
__global__ __launch_bounds__(256) void k_hist(const int* __restrict__ ei, int* __restrict__ cnt) {
    int i = blockIdx.x * blockDim.x + threadIdx.x;
    int stride = gridDim.x * blockDim.x;
    for (; i < N_EDGES; i += stride) atomicAdd(&cnt[ei[N_EDGES + i]], 1);
}

__global__ __launch_bounds__(256) void k_scan1(const int* __restrict__ cnt,
                                               int* __restrict__ inc, int* __restrict__ bsum) {
    __shared__ int sh[256];
    int gi = blockIdx.x * 256 + threadIdx.x;
    int v = (gi < N_NODES + 1) ? cnt[gi] : 0;
    sh[threadIdx.x] = v;
    __syncthreads();
    #pragma unroll
    for (int d = 1; d < 256; d <<= 1) {
        int t = (threadIdx.x >= d) ? sh[threadIdx.x - d] : 0;
        __syncthreads();
        sh[threadIdx.x] += t;
        __syncthreads();
    }
    if (gi < N_NODES + 1) inc[gi] = sh[threadIdx.x];
    if (threadIdx.x == 255) bsum[blockIdx.x] = sh[255];
}

__global__ __launch_bounds__(256) void k_scan2(int* __restrict__ bsum) {
    __shared__ int sh[256];
    int t = threadIdx.x;
    sh[t] = (t < SCAN_NB) ? bsum[t] : 0;
    __syncthreads();
    #pragma unroll
    for (int d = 1; d < 256; d <<= 1) {
        int v = (t >= d) ? sh[t - d] : 0;
        __syncthreads();
        sh[t] += v;
        __syncthreads();
    }
    if (t < SCAN_NB) bsum[t] = (t == 0) ? 0 : sh[t - 1];
}

__global__ __launch_bounds__(256) void k_scan3(const int* __restrict__ inc,
                                               const int* __restrict__ cnt,
                                               const int* __restrict__ bsum,
                                               int* __restrict__ offs, int* __restrict__ cursor) {
    int gi = blockIdx.x * 256 + threadIdx.x;
    if (gi < N_NODES + 1) {
        int e = bsum[blockIdx.x] + inc[gi] - cnt[gi];
        offs[gi] = e;
        if (gi < N_NODES) cursor[gi] = e;
    }
}

__global__ __launch_bounds__(256) void k_scatter(
    const int* __restrict__ ei, const float* __restrict__ eattr,
    int* __restrict__ cursor, int2* __restrict__ s_pack) {
    int i = blockIdx.x * blockDim.x + threadIdx.x;
    if (i >= N_EDGES) return;
    int d = ei[N_EDGES + i];
    int p = atomicAdd(&cursor[d], 1);
    int2 pk;
    pk.x = ei[i];
    pk.y = __float_as_int(eattr[i]);
    s_pack[p] = pk;
}

// ---------------- z = relu(LN(h, g, b)) ----------------
__global__ __launch_bounds__(256) void k_ln_relu(
    const float* __restrict__ h, const float* __restrict__ g,
    const float* __restrict__ b, float* __restrict__ z) {
    int wid = (blockIdx.x * blockDim.x + threadIdx.x) >> 6;
    int lane = threadIdx.x & 63;
    if (wid >= N_NODES) return;
    float v = h[wid * 64 + lane];
    float mu = waveReduceSum64(v) * (1.f / 64.f);
    float d = v - mu;
    float var = waveReduceSum64(d * d) * (1.f / 64.f);
    float zz = d * rsqrtf(var + 1e-5f) * g[lane] + b[lane];
    z[wid * 64 + lane] = fmaxf(zz, 0.f);
}

// ---------------- softmax aggregation, online, one wave per dst node ----------------
__global__ __launch_bounds__(256) void k_agg(
    const float* __restrict__ z, const int* __restrict__ offs,
    const int2* __restrict__ s_pack,
    const float* __restrict__ We, const float* __restrict__ be,
    const float* __restrict__ t, int layer, float* __restrict__ agg) {
    int wid = (blockIdx.x * blockDim.x + threadIdx.x) >> 6;
    int lane = threadIdx.x & 63;
    if (wid >= N_NODES) return;
    int beg = offs[wid], end = offs[wid + 1];
    float we = We[lane], bev = be[lane];
    float tl = t[layer];
    float m = -INFINITY, s = 0.f, num = 0.f;
    int i = beg;
    for (; i + 1 < end; i += 2) {
        int2 p0i = s_pack[i], p1i = s_pack[i + 1];
        float ea0 = __int_as_float(p0i.y), ea1 = __int_as_float(p1i.y);
        float msg0 = fmaxf(z[p0i.x * 64 + lane] + fmaf(ea0, we, bev), 0.f) + 1e-7f;
        float msg1 = fmaxf(z[p1i.x * 64 + lane] + fmaf(ea1, we, bev), 0.f) + 1e-7f;
        float lg0 = msg0 * tl, lg1 = msg1 * tl;
        float mn = fmaxf(m, fmaxf(lg0, lg1));
        float corr = __expf(m - mn);
        float p0 = __expf(lg0 - mn);
        float p1 = __expf(lg1 - mn);
        s = fmaf(s, corr, p0 + p1);
        num = fmaf(num, corr, fmaf(p0, msg0, p1 * msg1));
        m = mn;
    }
    if (i < end) {
        int2 pk = s_pack[i];
        float ea = __int_as_float(pk.y);
        float msg = fmaxf(z[pk.x * 64 + lane] + fmaf(ea, we, bev), 0.f) + 1e-7f;
        float lg = msg * tl;
        float mn = fmaxf(m, lg);
        float corr = __expf(m - mn);
        float p = __expf(lg - mn);
        s = fmaf(s, corr, p);
        num = fmaf(num, corr, p * msg);
        m = mn;
    }
    agg[wid * 64 + lane] = num / (s + 1e-16f);
}

// ---------------- fused MLP via MFMA bf16 (one wave per 16 nodes) ----------------
// u[16x128] = (agg+z)[16x64] @ W1 + b1 -> LN128 -> relu -> o[16x64] = u @ W2 + b2 (+res)
// Weights live in VGPRs as B-fragments; activations round-trip wave-private LDS.
// Layouts (m89-verified): A[m=lane&15][k=(lane>>4)*8+j]; B[k=(lane>>4)*8+j][n=lane&15];
// C/D: col=lane&15, row=(lane>>4)*4+reg.
__global__ __launch_bounds__(256) void k_mlp(
    const float* __restrict__ agg, const float* __restrict__ z,
    float* __restrict__ h, const float* __restrict__ W1, const float* __restrict__ b1,
    const float* __restrict__ g1, const float* __restrict__ be1,
    const float* __restrict__ W2, const float* __restrict__ b2, int addres) {
    __shared__ unsigned short vbuf[4][16 * 64];    // per-wave v (bf16)
    __shared__ unsigned short ubuf[4][16 * 128];   // per-wave u (bf16)
    int lane = threadIdx.x & 63;
    int wave = threadIdx.x >> 6;
    int col = lane & 15, quad = lane >> 4;
    unsigned short* vb = vbuf[wave];
    unsigned short* ub = ubuf[wave];

    // --- one-time: weight B-fragments into VGPRs (bf16) ---
    short8 w1f[2][8];
    #pragma unroll
    for (int s = 0; s < 2; ++s)
        #pragma unroll
        for (int t = 0; t < 8; ++t)
            #pragma unroll
            for (int j = 0; j < 8; ++j)
                w1f[s][t][j] = (short)f2bf(W1[(s * 32 + quad * 8 + j) * 128 + t * 16 + col]);
    short8 w2f[4][4];
    #pragma unroll
    for (int s = 0; s < 4; ++s)
        #pragma unroll
        for (int t = 0; t < 4; ++t)
            #pragma unroll
            for (int j = 0; j < 8; ++j)
                w2f[s][t][j] = (short)f2bf(W2[(s * 32 + quad * 8 + j) * 64 + t * 16 + col]);

    float b1f[8], g1f[8], e1f[8];
    #pragma unroll
    for (int t = 0; t < 8; ++t) {
        int ch = t * 16 + col;
        b1f[t] = b1[ch]; g1f[t] = g1[ch]; e1f[t] = be1[ch];
    }
    float b2f_[4];
    #pragma unroll
    for (int t = 0; t < 4; ++t) b2f_[t] = b2[t * 16 + col];

    int nd = lane >> 2;              // staging: node within tile
    int cg = (lane & 3) * 16;        // staging: channel block

    for (int g = blockIdx.x * 4 + wave; g < N_NODES / 16; g += gridDim.x * 4) {
        int n0 = g * 16;
        // --- stage v = agg+z as bf16 into LDS [16][64] ---
        const float4* ap = (const float4*)(agg + (size_t)(n0 + nd) * 64 + cg);
        const float4* zp = (const float4*)(z + (size_t)(n0 + nd) * 64 + cg);
        float vv[16];
        #pragma unroll
        for (int q = 0; q < 4; ++q) {
            float4 a4 = ap[q], z4 = zp[q];
            vv[q * 4 + 0] = a4.x + z4.x; vv[q * 4 + 1] = a4.y + z4.y;
            vv[q * 4 + 2] = a4.z + z4.z; vv[q * 4 + 3] = a4.w + z4.w;
        }
        unsigned int pk[8];
        #pragma unroll
        for (int i = 0; i < 8; ++i)
            pk[i] = (unsigned)f2bf(vv[2 * i]) | ((unsigned)f2bf(vv[2 * i + 1]) << 16);
        uint4* vdst = (uint4*)&vb[nd * 64 + cg];
        vdst[0] = make_uint4(pk[0], pk[1], pk[2], pk[3]);
        vdst[1] = make_uint4(pk[4], pk[5], pk[6], pk[7]);

        // --- GEMM1: au[8 tiles] = v @ W1 (wave-private LDS, no barrier needed) ---
        short8 a0 = *(const short8*)&vb[col * 64 + quad * 8];
        short8 a1 = *(const short8*)&vb[col * 64 + 32 + quad * 8];
        f32x4 au[8];
        #pragma unroll
        for (int t = 0; t < 8; ++t) {
            f32x4 c = {0.f, 0.f, 0.f, 0.f};
            c = __builtin_amdgcn_mfma_f32_16x16x32_bf16(a0, w1f[0][t], c, 0, 0, 0);
            c = __builtin_amdgcn_mfma_f32_16x16x32_bf16(a1, w1f[1][t], c, 0, 0, 0);
            au[t] = c;
        }
        // --- LN(128)+relu in C-layout; write u bf16 to LDS [16][128] ---
        #pragma unroll
        for (int r = 0; r < 4; ++r) {
            float sx = 0.f, sq = 0.f;
            #pragma unroll
            for (int t = 0; t < 8; ++t) {
                float v = au[t][r] + b1f[t];
                sx += v; sq += v * v;
            }
            #pragma unroll
            for (int mask = 1; mask < 16; mask <<= 1) {
                sx += __shfl_xor(sx, mask, 64);
                sq += __shfl_xor(sq, mask, 64);
            }
            float mu = sx * (1.f / 128.f);
            float var = sq * (1.f / 128.f) - mu * mu;
            float rs = rsqrtf(var + 1e-5f);
            int row = quad * 4 + r;
            #pragma unroll
            for (int t = 0; t < 8; ++t) {
                float v = au[t][r] + b1f[t];
                float y = fmaxf(fmaf((v - mu) * rs, g1f[t], e1f[t]), 0.f);
                ub[row * 128 + t * 16 + col] = f2bf(y);
            }
        }
        // --- GEMM2: o[4 tiles] = u @ W2 ---
        f32x4 oc[4];
        #pragma unroll
        for (int t = 0; t < 4; ++t) oc[t] = (f32x4){0.f, 0.f, 0.f, 0.f};
        #pragma unroll
        for (int s = 0; s < 4; ++s) {
            short8 a = *(const short8*)&ub[col * 128 + s * 32 + quad * 8];
            #pragma unroll
            for (int t = 0; t < 4; ++t)
                oc[t] = __builtin_amdgcn_mfma_f32_16x16x32_bf16(a, w2f[s][t], oc[t], 0, 0, 0);
        }
        // --- epilogue: bias (+residual) -> h ---
        #pragma unroll
        for (int t = 0; t < 4; ++t) {
            #pragma unroll
            for (int r = 0; r < 4; ++r) {
                int n = n0 + quad * 4 + r;
                int ch = t * 16 + col;
                float val = oc[t][r] + b2f_[t];
                float* hp = &h[(size_t)n * 64 + ch];
                if (addres) val += *hp;
                *hp = val;
            }
        }
    }
}

// ---------------- final LN/relu + global avg & max pool partials ----------------
__global__ __launch_bounds__(256) void k_pool(
    const float* __restrict__ h, const float* __restrict__ g, const float* __restrict__ b,
    float* __restrict__ psum, unsigned int* __restrict__ pmax) {
    int wid0 = (blockIdx.x * blockDim.x + threadIdx.x) >> 6;
    int lane = threadIdx.x & 63;
    int nw = (gridDim.x * blockDim.x) >> 6;
    float ga = g[lane], ba = b[lane];
    float lsum = 0.f, lmax = 0.f;
    for (int n = wid0; n < N_NODES; n += nw) {
        float v = h[n * 64 + lane];
        float mu = waveReduceSum64(v) * (1.f / 64.f);
        float d = v - mu;
        float var = waveReduceSum64(d * d) * (1.f / 64.f);
        float zz = fmaxf(d * rsqrtf(var + 1e-5f) * ga + ba, 0.f);
        lsum += zz;
        lmax = fmaxf(lmax, zz);
    }
    atomicAdd(&psum[lane], lsum);
    atomicMax(&pmax[lane], __float_as_uint(lmax));
}

// ---------------- head ----------------
__global__ __launch_bounds__(64) void k_head(
    const float* __restrict__ psum, const unsigned int* __restrict__ pmax,
    const float* __restrict__ Wl, const float* __restrict__ bl, float* __restrict__ out) {
    __shared__ float emb[64];
    int t = threadIdx.x;
    if (t < 32) {
        emb[t] = (psum[2 * t] + psum[2 * t + 1]) * (0.5f / (float)N_NODES);
    } else {
        int i = t - 32;
        emb[t] = fmaxf(__uint_as_float(pmax[2 * i]), __uint_as_float(pmax[2 * i + 1]));
    }
    __syncthreads();
    float acc = bl[t];
    for (int k = 0; k < 64; ++k) acc = fmaf(emb[k], Wl[k * 64 + t], acc);
    out[t] = acc;
}

extern "C" void kernel_launch(void* const* d_in, const int* in_sizes, int n_in,
                              void* d_out, int out_size, void* d_ws, size_t ws_size,
                              hipStream_t stream) {
    const float* x     = (const float*)d_in[0];
    const float* eattr = (const float*)d_in[1];
    const int*   ei    = (const int*)d_in[2];
    const float* Wn    = (const float*)d_in[3];
    const float* bn    = (const float*)d_in[4];
    const float* We    = (const float*)d_in[5];
    const float* be    = (const float*)d_in[6];
    const float* t     = (const float*)d_in[7];
    const float* W1    = (const float*)d_in[8];
    const float* b1    = (const float*)d_in[9];
    const float* lg    = (const float*)d_in[10];
    const float* lb    = (const float*)d_in[11];
    const float* W2    = (const float*)d_in[12];
    const float* b2    = (const float*)d_in[13];
    const float* ng    = (const float*)d_in[14];
    const float* nb    = (const float*)d_in[15];
    const float* Wl    = (const float*)d_in[16];
    const float* bl    = (const float*)d_in[17];
    float* out = (float*)d_out;

    char* p = (char*)d_ws;
    float* h   = (float*)p; p += (size_t)N_NODES * 64 * 4;
    float* z   = (float*)p; p += (size_t)N_NODES * 64 * 4;
    float* agg = (float*)p; p += (size_t)N_NODES * 64 * 4;
    int2* s_pack = (int2*)p; p += (size_t)N_EDGES * 8;
    int* cnt    = (int*)p;  p += (size_t)(N_NODES + 4) * 4;
    int* offs   = (int*)p;  p += (size_t)(N_NODES + 4) * 4;
    int* cursor = (int*)p;  p += (size_t)(N_NODES + 4) * 4;
    int* inc    = (int*)p;  p += (size_t)(N_NODES + 4) * 4;
    int* bsum   = (int*)p;  p += (size_t)256 * 4;
    float* psum = (float*)p; p += 64 * 4;
    unsigned int* pmax = (unsigned int*)p; p += 64 * 4;

    hipMemsetAsync(cnt, 0, (N_NODES + 1) * sizeof(int), stream);
    hipMemsetAsync(psum, 0, 64 * sizeof(float), stream);
    hipMemsetAsync(pmax, 0, 64 * sizeof(unsigned int), stream);

    k_node_encode<<<(N_NODES + 3) / 4, 256, 0, stream>>>(x, Wn, bn, h);
    k_hist<<<1024, 256, 0, stream>>>(ei, cnt);
    k_scan1<<<SCAN_NB, 256, 0, stream>>>(cnt, inc, bsum);
    k_scan2<<<1, 256, 0, stream>>>(bsum);
    k_scan3<<<SCAN_NB, 256, 0, stream>>>(inc, cnt, bsum, offs, cursor);
    k_scatter<<<(N_EDGES + 255) / 256, 256, 0, stream>>>(ei, eattr, cursor, s_pack);

    for (int i = 0; i < 3; ++i) {
        const float* zp;
        if (i > 0) {
            k_ln_relu<<<(N_NODES + 3) / 4, 256, 0, stream>>>(h, ng + i * 64, nb + i * 64, z);
            zp = z;
        } else {
            zp = h;
        }
        k_agg<<<(N_NODES + 3) / 4, 256, 0, stream>>>(zp, offs, s_pack, We, be, t, i, agg);
        k_mlp<<<391, 256, 0, stream>>>(
            agg, zp, h, W1 + (size_t)i * 64 * 128, b1 + i * 128, lg + i * 128, lb + i * 128,
            W2 + (size_t)i * 128 * 64, b2 + i * 64, i > 0);
    }

    k_pool<<<256, 256, 0, stream>>>(h, ng, nb, psum, pmax);
    k_head<<<1, 64, 0, stream>>>(psum, pmax, Wl, bl, out);
}

// Round 7
// 449.508 us; speedup vs baseline: 2.5192x; 1.2384x over previous
//
#include <hip/hip_runtime.h>
#include <math.h>

#define N_NODES 50000
#define N_EDGES 1000000
#define HID 64
#define SCAN_NB ((N_NODES + 1 + 255) / 256)
static_assert(N_NODES <= 65536, "src must fit in 16 bits");

typedef __attribute__((ext_vector_type(8))) short short8;   // 8 bf16 = 4 VGPRs
typedef __attribute__((ext_vector_type(4))) float f32x4;

__device__ __forceinline__ unsigned short f2bf(float x) {   // RNE float->bf16
    unsigned u = __float_as_uint(x);
    u += 0x7FFFu + ((u >> 16) & 1u);
    return (unsigned short)(u >> 16);
}
__device__ __forceinline__ float bfbits_hi(unsigned pk) {   // high-16 bf16 -> f32
    return __uint_as_float(pk & 0xFFFF0000u);
}
__device__ __forceinline__ float bf2f(unsigned short v) {
    return __uint_as_float(((unsigned)v) << 16);
}

__device__ __forceinline__ float waveReduceSum64(float v) {
    #pragma unroll
    for (int o = 32; o > 0; o >>= 1) v += __shfl_xor(v, o, 64);
    return v;
}

// ---------------- node encoder: h = x @ W_node + b_node (f32 + bf16 copies) ----------------
__global__ __launch_bounds__(256) void k_node_encode(
    const float* __restrict__ x, const float* __restrict__ Wn,
    const float* __restrict__ bn, float* __restrict__ h, unsigned short* __restrict__ hb) {
    int n = blockIdx.x * 4 + (threadIdx.x >> 6);
    int c = threadIdx.x & 63;
    if (n >= N_NODES) return;
    float acc = bn[c];
    const float* xr = x + n * 16;
    #pragma unroll
    for (int k = 0; k < 16; ++k) acc = fmaf(xr[k], Wn[k * 64 + c], acc);
    h[n * 64 + c] = acc;
    hb[n * 64 + c] = f2bf(acc);
}

// ---------------- edge CSR build: histogram + per-edge rank ----------------
__global__ __launch_bounds__(256) void k_hist_rank(const int* __restrict__ ei,
                                                   int* __restrict__ cnt, int* __restrict__ rank) {
    int i = blockIdx.x * blockDim.x + threadIdx.x;
    if (i >= N_EDGES) return;
    rank[i] = atomicAdd(&cnt[ei[N_EDGES + i]], 1);
}

__global__ __launch_bounds__(256) void k_scan1(const int* __restrict__ cnt,
                                               int* __restrict__ inc, int* __restrict__ bsum) {
    __shared__ int sh[256];
    int gi = blockIdx.x * 256 + threadIdx.x;
    int v = (gi < N_NODES + 1) ? cnt[gi] : 0;
    sh[threadIdx.x] = v;
    __syncthreads();
    #pragma unroll
    for (int d = 1; d < 256; d <<= 1) {
        int t = (threadIdx.x >= d) ? sh[threadIdx.x - d] : 0;
        __syncthreads();
        sh[threadIdx.x] += t;
        __syncthreads();
    }
    if (gi < N_NODES + 1) inc[gi] = sh[threadIdx.x];
    if (threadIdx.x == 255) bsum[blockIdx.x] = sh[255];
}

__global__ __launch_bounds__(256) void k_scan2(int* __restrict__ bsum) {
    __shared__ int sh[256];
    int t = threadIdx.x;
    sh[t] = (t < SCAN_NB) ? bsum[t] : 0;
    __syncthreads();
    #pragma unroll
    for (int d = 1; d < 256; d <<= 1) {
        int v = (t >= d) ? sh[t - d] : 0;
        __syncthreads();
        sh[t] += v;
        __syncthreads();
    }
    if (t < SCAN_NB) bsum[t] = (t == 0) ? 0 : sh[t - 1];
}

__global__ __launch_bounds__(256) void k_scan3(const int* __restrict__ inc,
                                               const int* __restrict__ cnt,
                                               const int* __restrict__ bsum,
                                               int* __restrict__ offs) {
    int gi = blockIdx.x * 256 + threadIdx.x;
    if (gi < N_NODES + 1) offs[gi] = bsum[blockIdx.x] + inc[gi] - cnt[gi];
}

// pure random 4B store, no atomics: p = offs[d] + rank[i]
__global__ __launch_bounds__(256) void k_scatter(
    const int* __restrict__ ei, const float* __restrict__ eattr,
    const int* __restrict__ offs, const int* __restrict__ rank,
    unsigned int* __restrict__ s_pack) {
    int i = blockIdx.x * blockDim.x + threadIdx.x;
    if (i >= N_EDGES) return;
    int d = ei[N_EDGES + i];
    int p = offs[d] + rank[i];
    unsigned pk = ((unsigned)f2bf(eattr[i]) << 16) | (unsigned)(ei[i] & 0xFFFF);
    s_pack[p] = pk;
}

// ---------------- z = relu(LN(h, g, b)) (f32 + bf16 copies) ----------------
__global__ __launch_bounds__(256) void k_ln_relu(
    const float* __restrict__ h, const float* __restrict__ g,
    const float* __restrict__ b, float* __restrict__ z, unsigned short* __restrict__ zb) {
    int wid = (blockIdx.x * blockDim.x + threadIdx.x) >> 6;
    int lane = threadIdx.x & 63;
    if (wid >= N_NODES) return;
    float v = h[wid * 64 + lane];
    float mu = waveReduceSum64(v) * (1.f / 64.f);
    float d = v - mu;
    float var = waveReduceSum64(d * d) * (1.f / 64.f);
    float zz = fmaxf(d * rsqrtf(var + 1e-5f) * g[lane] + b[lane], 0.f);
    z[wid * 64 + lane] = zz;
    zb[wid * 64 + lane] = f2bf(zz);
}

// ---------------- softmax aggregation, online, one wave per dst node ----------------
__global__ __launch_bounds__(256) void k_agg(
    const unsigned short* __restrict__ zb, const int* __restrict__ offs,
    const unsigned int* __restrict__ s_pack,
    const float* __restrict__ We, const float* __restrict__ be,
    const float* __restrict__ t, int layer, float* __restrict__ agg) {
    int wid = (blockIdx.x * blockDim.x + threadIdx.x) >> 6;
    int lane = threadIdx.x & 63;
    if (wid >= N_NODES) return;
    int beg = offs[wid], end = offs[wid + 1];
    float we = We[lane], bev = be[lane];
    float tl = t[layer];
    float m = -INFINITY, s = 0.f, num = 0.f;
    int i = beg;
    for (; i + 3 < end; i += 4) {
        unsigned pk0 = s_pack[i], pk1 = s_pack[i + 1], pk2 = s_pack[i + 2], pk3 = s_pack[i + 3];
        float z0 = bf2f(zb[(pk0 & 0xFFFFu) * 64 + lane]);
        float z1 = bf2f(zb[(pk1 & 0xFFFFu) * 64 + lane]);
        float z2 = bf2f(zb[(pk2 & 0xFFFFu) * 64 + lane]);
        float z3 = bf2f(zb[(pk3 & 0xFFFFu) * 64 + lane]);
        float msg0 = fmaxf(z0 + fmaf(bfbits_hi(pk0), we, bev), 0.f) + 1e-7f;
        float msg1 = fmaxf(z1 + fmaf(bfbits_hi(pk1), we, bev), 0.f) + 1e-7f;
        float msg2 = fmaxf(z2 + fmaf(bfbits_hi(pk2), we, bev), 0.f) + 1e-7f;
        float msg3 = fmaxf(z3 + fmaf(bfbits_hi(pk3), we, bev), 0.f) + 1e-7f;
        float lg0 = msg0 * tl, lg1 = msg1 * tl, lg2 = msg2 * tl, lg3 = msg3 * tl;
        float mn = fmaxf(m, fmaxf(fmaxf(lg0, lg1), fmaxf(lg2, lg3)));
        float corr = __expf(m - mn);
        float p0 = __expf(lg0 - mn), p1 = __expf(lg1 - mn);
        float p2 = __expf(lg2 - mn), p3 = __expf(lg3 - mn);
        s = fmaf(s, corr, (p0 + p1) + (p2 + p3));
        num = fmaf(num, corr, fmaf(p0, msg0, p1 * msg1) + fmaf(p2, msg2, p3 * msg3));
        m = mn;
    }
    for (; i < end; ++i) {
        unsigned pk = s_pack[i];
        float zz = bf2f(zb[(pk & 0xFFFFu) * 64 + lane]);
        float msg = fmaxf(zz + fmaf(bfbits_hi(pk), we, bev), 0.f) + 1e-7f;
        float lg = msg * tl;
        float mn = fmaxf(m, lg);
        float corr = __expf(m - mn);
        float p = __expf(lg - mn);
        s = fmaf(s, corr, p);
        num = fmaf(num, corr, p * msg);
        m = mn;
    }
    agg[wid * 64 + lane] = num / (s + 1e-16f);
}

// ---------------- fused MLP via MFMA bf16 (one wave per 16 nodes) ----------------
__global__ __launch_bounds__(256) void k_mlp(
    const float* __restrict__ agg, const float* __restrict__ z,
    float* __restrict__ h, const float* __restrict__ W1, const float* __restrict__ b1,
    const float* __restrict__ g1, const float* __restrict__ be1,
    const float* __restrict__ W2, const float* __restrict__ b2, int addres) {
    __shared__ unsigned short vbuf[4][16 * 64];
    __shared__ unsigned short ubuf[4][16 * 128];
    int lane = threadIdx.x & 63;
    int wave = threadIdx.x >> 6;
    int col = lane & 15, quad = lane >> 4;
    unsigned short* vb = vbuf[wave];
    unsigned short* ub = ubuf[wave];

    short8 w1f[2][8];
    #pragma unroll
    for (int s = 0; s < 2; ++s)
        #pragma unroll
        for (int t = 0; t < 8; ++t)
            #pragma unroll
            for (int j = 0; j < 8; ++j)
                w1f[s][t][j] = (short)f2bf(W1[(s * 32 + quad * 8 + j) * 128 + t * 16 + col]);
    short8 w2f[4][4];
    #pragma unroll
    for (int s = 0; s < 4; ++s)
        #pragma unroll
        for (int t = 0; t < 4; ++t)
            #pragma unroll
            for (int j = 0; j < 8; ++j)
                w2f[s][t][j] = (short)f2bf(W2[(s * 32 + quad * 8 + j) * 64 + t * 16 + col]);

    float b1f[8], g1f[8], e1f[8];
    #pragma unroll
    for (int t = 0; t < 8; ++t) {
        int ch = t * 16 + col;
        b1f[t] = b1[ch]; g1f[t] = g1[ch]; e1f[t] = be1[ch];
    }
    float b2f_[4];
    #pragma unroll
    for (int t = 0; t < 4; ++t) b2f_[t] = b2[t * 16 + col];

    int nd = lane >> 2;
    int cg = (lane & 3) * 16;

    for (int g = blockIdx.x * 4 + wave; g < N_NODES / 16; g += gridDim.x * 4) {
        int n0 = g * 16;
        const float4* ap = (const float4*)(agg + (size_t)(n0 + nd) * 64 + cg);
        const float4* zp = (const float4*)(z + (size_t)(n0 + nd) * 64 + cg);
        float vv[16];
        #pragma unroll
        for (int q = 0; q < 4; ++q) {
            float4 a4 = ap[q], z4 = zp[q];
            vv[q * 4 + 0] = a4.x + z4.x; vv[q * 4 + 1] = a4.y + z4.y;
            vv[q * 4 + 2] = a4.z + z4.z; vv[q * 4 + 3] = a4.w + z4.w;
        }
        unsigned int pk[8];
        #pragma unroll
        for (int i = 0; i < 8; ++i)
            pk[i] = (unsigned)f2bf(vv[2 * i]) | ((unsigned)f2bf(vv[2 * i + 1]) << 16);
        uint4* vdst = (uint4*)&vb[nd * 64 + cg];
        vdst[0] = make_uint4(pk[0], pk[1], pk[2], pk[3]);
        vdst[1] = make_uint4(pk[4], pk[5], pk[6], pk[7]);

        short8 a0 = *(const short8*)&vb[col * 64 + quad * 8];
        short8 a1 = *(const short8*)&vb[col * 64 + 32 + quad * 8];
        f32x4 au[8];
        #pragma unroll
        for (int t = 0; t < 8; ++t) {
            f32x4 c = {0.f, 0.f, 0.f, 0.f};
            c = __builtin_amdgcn_mfma_f32_16x16x32_bf16(a0, w1f[0][t], c, 0, 0, 0);
            c = __builtin_amdgcn_mfma_f32_16x16x32_bf16(a1, w1f[1][t], c, 0, 0, 0);
            au[t] = c;
        }
        #pragma unroll
        for (int r = 0; r < 4; ++r) {
            float sx = 0.f, sq = 0.f;
            #pragma unroll
            for (int t = 0; t < 8; ++t) {
                float v = au[t][r] + b1f[t];
                sx += v; sq += v * v;
            }
            #pragma unroll
            for (int mask = 1; mask < 16; mask <<= 1) {
                sx += __shfl_xor(sx, mask, 64);
                sq += __shfl_xor(sq, mask, 64);
            }
            float mu = sx * (1.f / 128.f);
            float var = sq * (1.f / 128.f) - mu * mu;
            float rs = rsqrtf(var + 1e-5f);
            int row = quad * 4 + r;
            #pragma unroll
            for (int t = 0; t < 8; ++t) {
                float v = au[t][r] + b1f[t];
                float y = fmaxf(fmaf((v - mu) * rs, g1f[t], e1f[t]), 0.f);
                ub[row * 128 + t * 16 + col] = f2bf(y);
            }
        }
        f32x4 oc[4];
        #pragma unroll
        for (int t = 0; t < 4; ++t) oc[t] = (f32x4){0.f, 0.f, 0.f, 0.f};
        #pragma unroll
        for (int s = 0; s < 4; ++s) {
            short8 a = *(const short8*)&ub[col * 128 + s * 32 + quad * 8];
            #pragma unroll
            for (int t = 0; t < 4; ++t)
                oc[t] = __builtin_amdgcn_mfma_f32_16x16x32_bf16(a, w2f[s][t], oc[t], 0, 0, 0);
        }
        #pragma unroll
        for (int t = 0; t < 4; ++t) {
            #pragma unroll
            for (int r = 0; r < 4; ++r) {
                int n = n0 + quad * 4 + r;
                int ch = t * 16 + col;
                float val = oc[t][r] + b2f_[t];
                float* hp = &h[(size_t)n * 64 + ch];
                if (addres) val += *hp;
                *hp = val;
            }
        }
    }
}

// ---------------- final LN/relu + global avg & max pool partials ----------------
__global__ __launch_bounds__(256) void k_pool(
    const float* __restrict__ h, const float* __restrict__ g, const float* __restrict__ b,
    float* __restrict__ psum, unsigned int* __restrict__ pmax) {
    int wid0 = (blockIdx.x * blockDim.x + threadIdx.x) >> 6;
    int lane = threadIdx.x & 63;
    int nw = (gridDim.x * blockDim.x) >> 6;
    float ga = g[lane], ba = b[lane];
    float lsum = 0.f, lmax = 0.f;
    for (int n = wid0; n < N_NODES; n += nw) {
        float v = h[n * 64 + lane];
        float mu = waveReduceSum64(v) * (1.f / 64.f);
        float d = v - mu;
        float var = waveReduceSum64(d * d) * (1.f / 64.f);
        float zz = fmaxf(d * rsqrtf(var + 1e-5f) * ga + ba, 0.f);
        lsum += zz;
        lmax = fmaxf(lmax, zz);
    }
    atomicAdd(&psum[lane], lsum);
    atomicMax(&pmax[lane], __float_as_uint(lmax));
}

// ---------------- head ----------------
__global__ __launch_bounds__(64) void k_head(
    const float* __restrict__ psum, const unsigned int* __restrict__ pmax,
    const float* __restrict__ Wl, const float* __restrict__ bl, float* __restrict__ out) {
    __shared__ float emb[64];
    int t = threadIdx.x;
    if (t < 32) {
        emb[t] = (psum[2 * t] + psum[2 * t + 1]) * (0.5f / (float)N_NODES);
    } else {
        int i = t - 32;
        emb[t] = fmaxf(__uint_as_float(pmax[2 * i]), __uint_as_float(pmax[2 * i + 1]));
    }
    __syncthreads();
    float acc = bl[t];
    for (int k = 0; k < 64; ++k) acc = fmaf(emb[k], Wl[k * 64 + t], acc);
    out[t] = acc;
}

extern "C" void kernel_launch(void* const* d_in, const int* in_sizes, int n_in,
                              void* d_out, int out_size, void* d_ws, size_t ws_size,
                              hipStream_t stream) {
    const float* x     = (const float*)d_in[0];
    const float* eattr = (const float*)d_in[1];
    const int*   ei    = (const int*)d_in[2];
    const float* Wn    = (const float*)d_in[3];
    const float* bn    = (const float*)d_in[4];
    const float* We    = (const float*)d_in[5];
    const float* be    = (const float*)d_in[6];
    const float* t     = (const float*)d_in[7];
    const float* W1    = (const float*)d_in[8];
    const float* b1    = (const float*)d_in[9];
    const float* lg    = (const float*)d_in[10];
    const float* lb    = (const float*)d_in[11];
    const float* W2    = (const float*)d_in[12];
    const float* b2    = (const float*)d_in[13];
    const float* ng    = (const float*)d_in[14];
    const float* nb    = (const float*)d_in[15];
    const float* Wl    = (const float*)d_in[16];
    const float* bl    = (const float*)d_in[17];
    float* out = (float*)d_out;

    char* p = (char*)d_ws;
    float* h   = (float*)p; p += (size_t)N_NODES * 64 * 4;
    float* z   = (float*)p; p += (size_t)N_NODES * 64 * 4;
    float* agg = (float*)p; p += (size_t)N_NODES * 64 * 4;
    unsigned short* zb = (unsigned short*)p; p += (size_t)N_NODES * 64 * 2;
    unsigned int* s_pack = (unsigned int*)p; p += (size_t)N_EDGES * 4;
    int* cnt    = (int*)p;  p += (size_t)(N_NODES + 4) * 4;
    int* offs   = (int*)p;  p += (size_t)(N_NODES + 4) * 4;
    int* inc    = (int*)p;  p += (size_t)(N_NODES + 4) * 4;
    int* bsum   = (int*)p;  p += (size_t)256 * 4;
    float* psum = (float*)p; p += 64 * 4;
    unsigned int* pmax = (unsigned int*)p; p += 64 * 4;
    int* rank = (int*)agg;   // aliases agg: rank dead before first k_agg write

    hipMemsetAsync(cnt, 0, (N_NODES + 1) * sizeof(int), stream);
    hipMemsetAsync(psum, 0, 64 * sizeof(float), stream);
    hipMemsetAsync(pmax, 0, 64 * sizeof(unsigned int), stream);

    k_node_encode<<<(N_NODES + 3) / 4, 256, 0, stream>>>(x, Wn, bn, h, zb);
    k_hist_rank<<<(N_EDGES + 255) / 256, 256, 0, stream>>>(ei, cnt, rank);
    k_scan1<<<SCAN_NB, 256, 0, stream>>>(cnt, inc, bsum);
    k_scan2<<<1, 256, 0, stream>>>(bsum);
    k_scan3<<<SCAN_NB, 256, 0, stream>>>(inc, cnt, bsum, offs);
    k_scatter<<<(N_EDGES + 255) / 256, 256, 0, stream>>>(ei, eattr, offs, rank, s_pack);

    for (int i = 0; i < 3; ++i) {
        const float* zp;
        if (i > 0) {
            k_ln_relu<<<(N_NODES + 3) / 4, 256, 0, stream>>>(h, ng + i * 64, nb + i * 64, z, zb);
            zp = z;
        } else {
            zp = h;   // zb already holds bf16(h) from k_node_encode
        }
        k_agg<<<(N_NODES + 3) / 4, 256, 0, stream>>>(zb, offs, s_pack, We, be, t, i, agg);
        k_mlp<<<391, 256, 0, stream>>>(
            agg, zp, h, W1 + (size_t)i * 64 * 128, b1 + i * 128, lg + i * 128, lb + i * 128,
            W2 + (size_t)i * 128 * 64, b2 + i * 64, i > 0);
    }

    k_pool<<<256, 256, 0, stream>>>(h, ng, nb, psum, pmax);
    k_head<<<1, 64, 0, stream>>>(psum, pmax, Wl, bl, out);
}